// Round 15
// baseline (2254.590 us; speedup 1.0000x reference)
//
#include <hip/hip_runtime.h>
#include <math.h>

// FISTA data-consistency with masked multi-coil 2D FFT operator.
// B=4, C=16, H=W=384.
// Register FFT: 384 = 6 (regs) x 64 (lanes); DIF leaves bit-reversed-permuted
// frequencies; mask is pre-permuted; DIT consumes permuted order (free).
// Twiddles: 32-entry register table (1 sincosf/kernel) via __shfl, PRE-SIGNED.
// Exchanges: h=1,2 DPP quad_perm (VALU); h=4..32 __shfl_xor (LDS pipe).
// Butterflies: fma/fold (R13). P2 (R15): 16-col tile, 4 columns per wave
// through one FFT body — R14 showed p2 pinned at 49us across 3 structures
// with VALU 51% & occ 33% -> dependency-chain latency-bound; 4-col ILP
// overlaps the chain 4-ways. 128B chunks also kill split-line overfetch.
// zk folded out: cz=(1-lam)cst+lam*z; 1/N folded into wb chain.
// R3: don't fuse p3+p1. R8: fp16 W1 FAILS (range). R9: builtins only.
// R11: keep live ranges short. R14: permlane builtin = ~5 VALU ops (avoid).

#define NN 384
#define BB 4
#define CC 16
#define NITER 20
#define LNPAD 432   // old LDS path (precompute only)
#define PI_F 3.14159265358979323846f
#define TWOPI_F 6.28318530717958647692f

__device__ __forceinline__ int LID(int i) { return i + (i >> 3); }

__device__ __forceinline__ float2 cmulf(float2 a, float2 b) {
  return make_float2(a.x * b.x - a.y * b.y, a.x * b.y + a.y * b.x);
}

// ---------------- cross-lane exchange primitives ---------------------------
template<int CTRL>
__device__ __forceinline__ float dppx(float v) {
  int s = __float_as_int(v);
  return __int_as_float(__builtin_amdgcn_update_dpp(s, s, CTRL, 0xF, 0xF, true));
}

template<int H>
__device__ __forceinline__ float2 exch(float2 v) {
  if constexpr (H == 1) {
    return make_float2(dppx<0xB1>(v.x), dppx<0xB1>(v.y));   // [1,0,3,2]
  } else if constexpr (H == 2) {
    return make_float2(dppx<0x4E>(v.x), dppx<0x4E>(v.y));   // [2,3,0,1]
  } else {
    return make_float2(__shfl_xor(v.x, H), __shfl_xor(v.y, H));
  }
}

template<int DIR>
__device__ __forceinline__ void dft4(float2* v) {
  float ax = v[0].x + v[2].x, ay = v[0].y + v[2].y;
  float bx = v[0].x - v[2].x, by = v[0].y - v[2].y;
  float cx = v[1].x + v[3].x, cy = v[1].y + v[3].y;
  float dx = v[1].x - v[3].x, dy = v[1].y - v[3].y;
  float dix, diy;
  if (DIR < 0) { dix = dy; diy = -dx; }
  else         { dix = -dy; diy = dx; }
  v[0] = make_float2(ax + cx, ay + cy);
  v[2] = make_float2(ax - cx, ay - cy);
  v[1] = make_float2(bx + dix, by + diy);
  v[3] = make_float2(bx - dix, by - diy);
}

// DFT-3: X1 = m + i*s*S3*d, X2 = m - i*s*S3*d; m = a - u/2, u=b+c, d=b-c.
template<int SIGN>
__device__ __forceinline__ void dft3(float2 a, float2 b, float2 c,
                                     float2& X0, float2& X1, float2& X2) {
  const float S3 = 0.86602540378443864676f;
  float ux = b.x + c.x, uy = b.y + c.y;
  float dx = b.x - c.x, dy = b.y - c.y;
  float mx = a.x - 0.5f * ux, my = a.y - 0.5f * uy;
  float ex = S3 * dx, ey = S3 * dy;
  X0 = make_float2(a.x + ux, a.y + uy);
  if (SIGN < 0) {
    X1 = make_float2(mx + ey, my - ex);
    X2 = make_float2(mx - ey, my + ex);
  } else {
    X1 = make_float2(mx - ey, my + ex);
    X2 = make_float2(mx + ey, my - ex);
  }
}

// Fast DFT-6 = two DFT-3 + trivial W6 twiddles. Verified on impulses.
template<int SIGN>
__device__ __forceinline__ void dft6(float2* v) {
  const float S3 = 0.86602540378443864676f;
  float2 E0, E1, E2, O0, O1, O2;
  dft3<SIGN>(v[0], v[2], v[4], E0, E1, E2);
  dft3<SIGN>(v[1], v[3], v[5], O0, O1, O2);
  const float ss = (SIGN < 0) ? -S3 : S3;
  float2 T1 = cmulf(O1, make_float2(0.5f, ss));
  float2 T2 = cmulf(O2, make_float2(-0.5f, ss));
  v[0] = make_float2(E0.x + O0.x, E0.y + O0.y);
  v[1] = make_float2(E1.x + T1.x, E1.y + T1.y);
  v[2] = make_float2(E2.x + T2.x, E2.y + T2.y);
  v[3] = make_float2(E0.x - O0.x, E0.y - O0.y);
  v[4] = make_float2(E1.x - T1.x, E1.y - T1.y);
  v[5] = make_float2(E2.x - T2.x, E2.y - T2.y);
}

// ---------------- register FFT machinery (iteration path) ------------------
// fma/fold butterflies. Per stage (lane-hoisted): s = hi?-1:1,
// (csl,snl) = hi?(cs,sn):(1,0). Lo-lane cmul by (1,0) is exact.

// ---- single-column steps (p1) ----
template<int H>
__device__ __forceinline__ void dif_step1(float2 v[6], float s, float csl, float snl) {
#pragma unroll
  for (int r = 0; r < 6; ++r) {
    float2 o = exch<H>(v[r]);
    float dx = fmaf(s, v[r].x, o.x);
    float dy = fmaf(s, v[r].y, o.y);
    v[r] = make_float2(dx * csl - dy * snl, dx * snl + dy * csl);
  }
}
template<int H>
__device__ __forceinline__ void dif_step1_notw(float2 v[6], float s) {
#pragma unroll
  for (int r = 0; r < 6; ++r) {
    float2 o = exch<H>(v[r]);
    v[r] = make_float2(fmaf(s, v[r].x, o.x), fmaf(s, v[r].y, o.y));
  }
}

// ---- dual-column steps (p3) ----
template<int H>
__device__ __forceinline__ void dit_step2(float2 u[6], float2 v[6],
                                          float s, float csl, float snl) {
#pragma unroll
  for (int r = 0; r < 6; ++r) {
    float2 bu = make_float2(u[r].x * csl - u[r].y * snl, u[r].x * snl + u[r].y * csl);
    float2 bv = make_float2(v[r].x * csl - v[r].y * snl, v[r].x * snl + v[r].y * csl);
    float2 ou = exch<H>(bu);
    float2 ov = exch<H>(bv);
    u[r] = make_float2(fmaf(s, bu.x, ou.x), fmaf(s, bu.y, ou.y));
    v[r] = make_float2(fmaf(s, bv.x, ov.x), fmaf(s, bv.y, ov.y));
  }
}
template<int H>
__device__ __forceinline__ void dit_step2_notw(float2 u[6], float2 v[6], float s) {
#pragma unroll
  for (int r = 0; r < 6; ++r) {
    float2 ou = exch<H>(u[r]);
    float2 ov = exch<H>(v[r]);
    u[r] = make_float2(fmaf(s, u[r].x, ou.x), fmaf(s, u[r].y, ou.y));
    v[r] = make_float2(fmaf(s, v[r].x, ov.x), fmaf(s, v[r].y, ov.y));
  }
}

// ---- quad-column steps (p2) ----
template<int H>
__device__ __forceinline__ void dif_step4(float2 q[4][6], float s, float csl, float snl) {
#pragma unroll
  for (int c = 0; c < 4; ++c)
#pragma unroll
    for (int r = 0; r < 6; ++r) {
      float2 o = exch<H>(q[c][r]);
      float dx = fmaf(s, q[c][r].x, o.x);
      float dy = fmaf(s, q[c][r].y, o.y);
      q[c][r] = make_float2(dx * csl - dy * snl, dx * snl + dy * csl);
    }
}
template<int H>
__device__ __forceinline__ void dif_step4_notw(float2 q[4][6], float s) {
#pragma unroll
  for (int c = 0; c < 4; ++c)
#pragma unroll
    for (int r = 0; r < 6; ++r) {
      float2 o = exch<H>(q[c][r]);
      q[c][r] = make_float2(fmaf(s, q[c][r].x, o.x), fmaf(s, q[c][r].y, o.y));
    }
}
template<int H>
__device__ __forceinline__ void dit_step4(float2 q[4][6], float s, float csl, float snl) {
#pragma unroll
  for (int c = 0; c < 4; ++c)
#pragma unroll
    for (int r = 0; r < 6; ++r) {
      float2 bt = make_float2(q[c][r].x * csl - q[c][r].y * snl,
                              q[c][r].x * snl + q[c][r].y * csl);
      float2 o = exch<H>(bt);
      q[c][r] = make_float2(fmaf(s, bt.x, o.x), fmaf(s, bt.y, o.y));
    }
}
template<int H>
__device__ __forceinline__ void dit_step4_notw(float2 q[4][6], float s) {
#pragma unroll
  for (int c = 0; c < 4; ++c)
#pragma unroll
    for (int r = 0; r < 6; ++r) {
      float2 o = exch<H>(q[c][r]);
      q[c][r] = make_float2(fmaf(s, q[c][r].x, o.x), fmaf(s, q[c][r].y, o.y));
    }
}

// ---- DIF drivers ----
template<int SIGN>
__device__ __forceinline__ void dif64t(float2 v[6], int t, float tc, float tss) {
  { int j = t & 31; bool hi = (t & 32) != 0;
    float cs = __shfl(tc, j), sn = __shfl(tss, j);
    float s = hi ? -1.f : 1.f, csl = hi ? cs : 1.f, snl = hi ? sn : 0.f;
    dif_step1<32>(v, s, csl, snl); }
  { int j = (t & 15) << 1; bool hi = (t & 16) != 0;
    float cs = __shfl(tc, j), sn = __shfl(tss, j);
    float s = hi ? -1.f : 1.f, csl = hi ? cs : 1.f, snl = hi ? sn : 0.f;
    dif_step1<16>(v, s, csl, snl); }
  { int j = (t & 7) << 2; bool hi = (t & 8) != 0;
    float cs = __shfl(tc, j), sn = __shfl(tss, j);
    float s = hi ? -1.f : 1.f, csl = hi ? cs : 1.f, snl = hi ? sn : 0.f;
    dif_step1<8>(v, s, csl, snl); }
  { int j = (t & 3) << 3; bool hi = (t & 4) != 0;
    float cs = __shfl(tc, j), sn = __shfl(tss, j);
    float s = hi ? -1.f : 1.f, csl = hi ? cs : 1.f, snl = hi ? sn : 0.f;
    dif_step1<4>(v, s, csl, snl); }
  { bool hi = (t & 2) != 0, iq = (t & 1) != 0;
    float s = hi ? -1.f : 1.f;
    float c2 = (hi && iq) ? 0.f : 1.f;
    float s2 = (hi && iq) ? (float)SIGN : 0.f;
    dif_step1<2>(v, s, c2, s2); }
  { bool hi = (t & 1) != 0;
    float s = hi ? -1.f : 1.f;
    dif_step1_notw<1>(v, s); }
}

template<int SIGN>
__device__ __forceinline__ void dif64t4(float2 q[4][6], int t, float tc, float tss) {
  { int j = t & 31; bool hi = (t & 32) != 0;                  // h=32
    float cs = __shfl(tc, j), sn = __shfl(tss, j);
    float s = hi ? -1.f : 1.f, csl = hi ? cs : 1.f, snl = hi ? sn : 0.f;
    dif_step4<32>(q, s, csl, snl); }
  { int j = (t & 15) << 1; bool hi = (t & 16) != 0;           // h=16
    float cs = __shfl(tc, j), sn = __shfl(tss, j);
    float s = hi ? -1.f : 1.f, csl = hi ? cs : 1.f, snl = hi ? sn : 0.f;
    dif_step4<16>(q, s, csl, snl); }
  { int j = (t & 7) << 2; bool hi = (t & 8) != 0;             // h=8
    float cs = __shfl(tc, j), sn = __shfl(tss, j);
    float s = hi ? -1.f : 1.f, csl = hi ? cs : 1.f, snl = hi ? sn : 0.f;
    dif_step4<8>(q, s, csl, snl); }
  { int j = (t & 3) << 3; bool hi = (t & 4) != 0;             // h=4
    float cs = __shfl(tc, j), sn = __shfl(tss, j);
    float s = hi ? -1.f : 1.f, csl = hi ? cs : 1.f, snl = hi ? sn : 0.f;
    dif_step4<4>(q, s, csl, snl); }
  { bool hi = (t & 2) != 0, iq = (t & 1) != 0;                // h=2 (DPP)
    float s = hi ? -1.f : 1.f;
    float c2 = (hi && iq) ? 0.f : 1.f;
    float s2 = (hi && iq) ? (float)SIGN : 0.f;
    dif_step4<2>(q, s, c2, s2); }
  { bool hi = (t & 1) != 0;                                   // h=1 (DPP, tw=1)
    float s = hi ? -1.f : 1.f;
    dif_step4_notw<1>(q, s); }
}

// ---- DIT drivers ----
template<int SIGN>
__device__ __forceinline__ void dit64t2(float2 u[6], float2 v[6], int t,
                                        float tc, float tss) {
  { bool hi = (t & 1) != 0;
    float s = hi ? -1.f : 1.f;
    dit_step2_notw<1>(u, v, s); }
  { bool hi = (t & 2) != 0, iq = (t & 1) != 0;
    float s = hi ? -1.f : 1.f;
    float c2 = (hi && iq) ? 0.f : 1.f;
    float s2 = (hi && iq) ? (float)SIGN : 0.f;
    dit_step2<2>(u, v, s, c2, s2); }
  { int j = (t & 3) << 3; bool hi = (t & 4) != 0;
    float cs = __shfl(tc, j), sn = __shfl(tss, j);
    float s = hi ? -1.f : 1.f, csl = hi ? cs : 1.f, snl = hi ? sn : 0.f;
    dit_step2<4>(u, v, s, csl, snl); }
  { int j = (t & 7) << 2; bool hi = (t & 8) != 0;
    float cs = __shfl(tc, j), sn = __shfl(tss, j);
    float s = hi ? -1.f : 1.f, csl = hi ? cs : 1.f, snl = hi ? sn : 0.f;
    dit_step2<8>(u, v, s, csl, snl); }
  { int j = (t & 15) << 1; bool hi = (t & 16) != 0;
    float cs = __shfl(tc, j), sn = __shfl(tss, j);
    float s = hi ? -1.f : 1.f, csl = hi ? cs : 1.f, snl = hi ? sn : 0.f;
    dit_step2<16>(u, v, s, csl, snl); }
  { int j = t & 31; bool hi = (t & 32) != 0;
    float cs = __shfl(tc, j), sn = __shfl(tss, j);
    float s = hi ? -1.f : 1.f, csl = hi ? cs : 1.f, snl = hi ? sn : 0.f;
    dit_step2<32>(u, v, s, csl, snl); }
}

template<int SIGN>
__device__ __forceinline__ void dit64t4(float2 q[4][6], int t, float tc, float tss) {
  { bool hi = (t & 1) != 0;                                   // h=1 (DPP, tw=1)
    float s = hi ? -1.f : 1.f;
    dit_step4_notw<1>(q, s); }
  { bool hi = (t & 2) != 0, iq = (t & 1) != 0;                // h=2 (DPP)
    float s = hi ? -1.f : 1.f;
    float c2 = (hi && iq) ? 0.f : 1.f;
    float s2 = (hi && iq) ? (float)SIGN : 0.f;
    dit_step4<2>(q, s, c2, s2); }
  { int j = (t & 3) << 3; bool hi = (t & 4) != 0;             // h=4
    float cs = __shfl(tc, j), sn = __shfl(tss, j);
    float s = hi ? -1.f : 1.f, csl = hi ? cs : 1.f, snl = hi ? sn : 0.f;
    dit_step4<4>(q, s, csl, snl); }
  { int j = (t & 7) << 2; bool hi = (t & 8) != 0;             // h=8
    float cs = __shfl(tc, j), sn = __shfl(tss, j);
    float s = hi ? -1.f : 1.f, csl = hi ? cs : 1.f, snl = hi ? sn : 0.f;
    dit_step4<8>(q, s, csl, snl); }
  { int j = (t & 15) << 1; bool hi = (t & 16) != 0;           // h=16
    float cs = __shfl(tc, j), sn = __shfl(tss, j);
    float s = hi ? -1.f : 1.f, csl = hi ? cs : 1.f, snl = hi ? sn : 0.f;
    dit_step4<16>(q, s, csl, snl); }
  { int j = t & 31; bool hi = (t & 32) != 0;                  // h=32
    float cs = __shfl(tc, j), sn = __shfl(tss, j);
    float s = hi ? -1.f : 1.f, csl = hi ? cs : 1.f, snl = hi ? sn : 0.f;
    dit_step4<32>(q, s, csl, snl); }
}

// FWD single: natural in -> permuted out. w[r-1] = exp(SIGN*2pi*i*r*t/384).
template<int SIGN>
__device__ __forceinline__ void fwd384t(float2 v[6], int t, float tc, float tss,
                                        const float2 w[5]) {
  dft6<SIGN>(v);
#pragma unroll
  for (int r = 1; r < 6; ++r) v[r] = cmulf(v[r], w[r - 1]);
  dif64t<SIGN>(v, t, tc, tss);
}

// FWD quad (p2)
template<int SIGN>
__device__ __forceinline__ void fwd384t4(float2 q[4][6], int t, float tc,
                                         float tss, const float2 w[5]) {
#pragma unroll
  for (int c = 0; c < 4; ++c) dft6<SIGN>(q[c]);
#pragma unroll
  for (int c = 0; c < 4; ++c)
#pragma unroll
    for (int r = 1; r < 6; ++r) q[c][r] = cmulf(q[c][r], w[r - 1]);
  dif64t4<SIGN>(q, t, tc, tss);
}

// BWD quad (p2): permuted in -> natural out; sc0 scales the r=0 term.
template<int SIGN>
__device__ __forceinline__ void bwd384t4(float2 q[4][6], int t, float tc,
                                         float tss, const float2 w[5], float sc0) {
  dit64t4<SIGN>(q, t, tc, tss);
#pragma unroll
  for (int c = 0; c < 4; ++c) {
    q[c][0].x *= sc0; q[c][0].y *= sc0;
#pragma unroll
    for (int r = 1; r < 6; ++r) q[c][r] = cmulf(q[c][r], w[r - 1]);
    dft6<SIGN>(q[c]);
  }
}

// BWD dual (p3)
template<int SIGN>
__device__ __forceinline__ void bwd384t2(float2 u[6], float2 v[6], int t,
                                         float tc, float tss, const float2 w[5],
                                         float sc0) {
  dit64t2<SIGN>(u, v, t, tc, tss);
  u[0].x *= sc0; u[0].y *= sc0;
  v[0].x *= sc0; v[0].y *= sc0;
#pragma unroll
  for (int r = 1; r < 6; ++r) { u[r] = cmulf(u[r], w[r - 1]); v[r] = cmulf(v[r], w[r - 1]); }
  dft6<SIGN>(u);
  dft6<SIGN>(v);
}

// ---------------- old LDS fft384 (precompute kernels only) -----------------
template<int R, int NS, int DIR>
__device__ __forceinline__ void fft_stage(const float2* S, float2* D, int t) {
  constexpr int NR = NN / R;
#pragma unroll
  for (int rep = 0; rep < (NR + 63) / 64; ++rep) {
    int j = t + rep * 64;
    if (j < NR) {
      float2 v[R];
#pragma unroll
      for (int r = 0; r < R; ++r) v[r] = S[LID(j + r * NR)];
      if constexpr (NS > 1) {
        float ang = (float)DIR * (TWOPI_F / (float)(NS * R)) * (float)(j % NS);
        float sv, cv;
        __sincosf(ang, &sv, &cv);
        float2 w = make_float2(cv, sv);
        float2 wr = w;
#pragma unroll
        for (int r = 1; r < R; ++r) { v[r] = cmulf(v[r], wr); wr = cmulf(wr, w); }
      }
      if constexpr (R == 4) dft4<DIR>(v); else dft6<DIR>(v);
      int base = (j / NS) * (NS * R) + (j % NS);
#pragma unroll
      for (int r = 0; r < R; ++r) D[LID(base + r * NS)] = v[r];
    }
  }
}

template<int DIR>
__device__ __forceinline__ void fft384(float2* A, float2* Bf, int t) {
  fft_stage<4, 1,  DIR>(A,  Bf, t); __syncthreads();
  fft_stage<4, 4,  DIR>(Bf, A,  t); __syncthreads();
  fft_stage<4, 16, DIR>(A,  Bf, t); __syncthreads();
  fft_stage<6, 64, DIR>(Bf, A,  t); __syncthreads();
}

// ---------------- E: iteration 1 (y0 = 0 -> xn = cz), elementwise ----------
__global__ __launch_bounds__(256) void k_e(const float2* __restrict__ czb,
                                           float2* __restrict__ xbuf,
                                           float2* __restrict__ ybuf) {
  long i = (long)blockIdx.x * 256 + threadIdx.x;
  float2 cz = czb[i];
  float2 x = make_float2(fmaxf(cz.x, 0.f), fmaxf(cz.y, 0.f));
  xbuf[i] = x;
  ybuf[i] = x;   // t1 = 1 -> y1 = x1
}

// ---------------- P1: row FFT of coil*y -> W1 (permuted-x storage) ---------
// grid B*C*384/4, 256 thr; one wave per row; no LDS, no barriers.
__global__ __launch_bounds__(256) void k_p1(const float2* __restrict__ ybuf,
                                            const float* __restrict__ csm,
                                            float2* __restrict__ W1) {
  int t = threadIdx.x & 63;
  int w = threadIdx.x >> 6;
  long gl = (long)blockIdx.x * 4 + w;       // (b*C + c)*384 + y
  int y = (int)(gl % NN);
  long bc = gl / NN;
  long b = bc >> 4, c = bc & 15;
  long rowoff = (long)y * NN;
  float tc, ts; __sincosf((float)(t & 31) * (PI_F / 32.0f), &ts, &tc);
  float tsf = -ts;                           // fwd (SIGN=-1) pre-signed
  float2 w0; __sincosf(-(float)t * (TWOPI_F / 384.0f), &w0.y, &w0.x);
  float2 wf[5];
  wf[0] = w0;
#pragma unroll
  for (int r = 1; r < 5; ++r) wf[r] = cmulf(wf[r - 1], w0);
  const float2* yrow = ybuf + b * (long)(NN * NN) + rowoff;
  const float* crow_re = csm + (b * 2 * CC + c) * (long)(NN * NN) + rowoff;
  const float* crow_im = crow_re + (long)CC * NN * NN;
  float2 v[6];
#pragma unroll
  for (int k = 0; k < 6; ++k) {
    int x = t + 64 * k;
    float2 yv = yrow[x];
    float cre = crow_re[x], cim = crow_im[x];
    v[k] = make_float2(yv.x * cre - yv.y * cim, yv.x * cim + yv.y * cre);
  }
  fwd384t<-1>(v, t, tc, tsf, wf);
  float2* orow = W1 + gl * NN;
#pragma unroll
  for (int r = 0; r < 6; ++r) orow[t + 64 * r] = v[r];
}

// ---------------- P2: col FFT -> mask -> col IFFT, in-place on W1 ----------
// grid B*C*(N/16)=1536 blocks, 256 thr. 16-col planar tile (50.2 KB, pad 392);
// 4 waves x 4 columns each through one FFT body (4-way chain ILP).
// float4 fill/drain in 128B row chunks. XCD-chunked swizzle.
#define P2PAD 392
__global__ __launch_bounds__(256) void k_p2(float2* __restrict__ W1,
                                            const unsigned char* __restrict__ maskPT) {
  __shared__ float ldsR[16][P2PAD];
  __shared__ float ldsI[16][P2PAD];
  int tid = threadIdx.x;
  const int nwg = BB * CC * (NN / 16);           // 1536, divisible by 8
  int l = ((int)blockIdx.x & 7) * (nwg >> 3) + ((int)blockIdx.x >> 3);
  int xt = l % (NN / 16);
  long bc = l / (NN / 16);
  long b = bc >> 4;
  int s0 = xt * 16;
  long sbase = bc * (long)(NN * NN);
  int w = tid >> 6, t = tid & 63;
  // twiddle setup: table (pre-signed per direction) + outer chains
  float tc, ts; __sincosf((float)(t & 31) * (PI_F / 32.0f), &ts, &tc);
  float tsf = -ts;
  float2 w0; __sincosf(-(float)t * (TWOPI_F / 384.0f), &w0.y, &w0.x);
  float2 wf[5], wb[5];
  wf[0] = w0;
#pragma unroll
  for (int r = 1; r < 5; ++r) wf[r] = cmulf(wf[r - 1], w0);
  const float inv = 1.0f / NN;
#pragma unroll
  for (int r = 0; r < 5; ++r) wb[r] = make_float2(wf[r].x * inv, -wf[r].y * inv);
  // fill: float4 (2 complex) per op; 8 float4 per row; 12 ops/thread
  const float4* W1v = (const float4*)W1;
  long f4base = (sbase >> 1) + (s0 >> 1);
#pragma unroll
  for (int k = 0; k < 12; ++k) {
    int e = tid + k * 256; int y = e >> 3; int q8 = e & 7;
    float4 val = W1v[f4base + (long)y * (NN / 2) + q8];
    ldsR[2 * q8][y] = val.x; ldsI[2 * q8][y] = val.y;
    ldsR[2 * q8 + 1][y] = val.z; ldsI[2 * q8 + 1][y] = val.w;
  }
  __syncthreads();
  const unsigned char* mb = maskPT + b * (long)(NN * NN);
  {
    float2 q[4][6];
#pragma unroll
    for (int c = 0; c < 4; ++c)
#pragma unroll
      for (int k = 0; k < 6; ++k)
        q[c][k] = make_float2(ldsR[w * 4 + c][t + 64 * k],
                              ldsI[w * 4 + c][t + 64 * k]);
    fwd384t4<-1>(q, t, tc, tsf, wf);
#pragma unroll
    for (int c = 0; c < 4; ++c) {
      const unsigned char* mc = mb + (long)(s0 + w * 4 + c) * NN;
#pragma unroll
      for (int r = 0; r < 6; ++r) {
        float mv = (float)mc[t + 64 * r];
        q[c][r].x *= mv; q[c][r].y *= mv;
      }
    }
    bwd384t4<1>(q, t, tc, ts, wb, inv);
#pragma unroll
    for (int c = 0; c < 4; ++c)
#pragma unroll
      for (int k = 0; k < 6; ++k) {
        ldsR[w * 4 + c][t + 64 * k] = q[c][k].x;
        ldsI[w * 4 + c][t + 64 * k] = q[c][k].y;
      }
  }
  __syncthreads();
  float4* W1o = (float4*)W1;
#pragma unroll
  for (int k = 0; k < 12; ++k) {
    int e = tid + k * 256; int y = e >> 3; int q8 = e & 7;
    float4 val;
    val.x = ldsR[2 * q8][y]; val.y = ldsI[2 * q8][y];
    val.z = ldsR[2 * q8 + 1][y]; val.w = ldsI[2 * q8 + 1][y];
    W1o[f4base + (long)y * (NN / 2) + q8] = val;
  }
}

// ---------------- P3: row IFFT + conj(coil) reduce + FISTA update ----------
// grid B*384 blocks, 256 thr; wave w handles coils 4w..4w+3 (2 at a time);
// LDS reduce. Update: x = prox((1-lam)(y - Q) + cz); zk not touched.
// last!=0: write planar output instead of x/y (final iteration).
__global__ __launch_bounds__(256) void k_p3(const float2* __restrict__ W1,
                                            const float* __restrict__ csm,
                                            const float2* __restrict__ czb,
                                            const float* __restrict__ lamp,
                                            float2* __restrict__ xbuf,
                                            float2* __restrict__ ybuf,
                                            float* __restrict__ outp,
                                            float beta, int last) {
  __shared__ float2 part[4][NN];
  int tid = threadIdx.x;
  int w = tid >> 6, t = tid & 63;
  long gl = blockIdx.x;            // b*384 + y
  long b = gl / NN;
  int y = (int)(gl % NN);
  long rowoff = (long)y * NN;
  float tc, ts; __sincosf((float)(t & 31) * (PI_F / 32.0f), &ts, &tc);
  float2 w0; __sincosf((float)t * (TWOPI_F / 384.0f), &w0.y, &w0.x);
  float2 wb[5];
  wb[0] = w0;
#pragma unroll
  for (int r = 1; r < 5; ++r) wb[r] = cmulf(wb[r - 1], w0);
  float2 acc[6];
#pragma unroll
  for (int k = 0; k < 6; ++k) acc[k] = make_float2(0.f, 0.f);
#pragma unroll
  for (int ci = 0; ci < 4; ci += 2) {
    int c0 = w * 4 + ci, c1 = c0 + 1;
    const float2* row0 = W1 + ((b * CC + c0) * (long)NN + y) * NN;
    const float2* row1 = W1 + ((b * CC + c1) * (long)NN + y) * NN;
    float2 u[6], v[6];
#pragma unroll
    for (int r = 0; r < 6; ++r) { u[r] = row0[t + 64 * r]; v[r] = row1[t + 64 * r]; }
    bwd384t2<1>(u, v, t, tc, ts, wb, 1.0f);
    const float* cre0 = csm + (b * 2 * CC + c0) * (long)(NN * NN) + rowoff;
    const float* cim0 = cre0 + (long)CC * NN * NN;
    const float* cre1 = csm + (b * 2 * CC + c1) * (long)(NN * NN) + rowoff;
    const float* cim1 = cre1 + (long)CC * NN * NN;
#pragma unroll
    for (int k = 0; k < 6; ++k) {
      int x = t + 64 * k;
      float a0 = cre0[x], b0 = cim0[x];
      float a1 = cre1[x], b1 = cim1[x];
      acc[k].x += (a0 * u[k].x + b0 * u[k].y) + (a1 * v[k].x + b1 * v[k].y);
      acc[k].y += (a0 * u[k].y - b0 * u[k].x) + (a1 * v[k].y - b1 * v[k].x);
    }
  }
#pragma unroll
  for (int k = 0; k < 6; ++k) part[w][t + 64 * k] = acc[k];
  __syncthreads();
  float lamv = lamp[0];
  float oml = 1.0f - lamv;
  long pbase = b * (long)(NN * NN) + rowoff;
  for (int e = tid; e < NN; e += 256) {
    float Qx = (part[0][e].x + part[1][e].x + part[2][e].x + part[3][e].x) * (1.0f / NN);
    float Qy = (part[0][e].y + part[1][e].y + part[2][e].y + part[3][e].y) * (1.0f / NN);
    float2 yv = ybuf[pbase + e];
    float2 cz = czb[pbase + e];
    float xr = oml * (yv.x - Qx) + cz.x;
    float xi = oml * (yv.y - Qy) + cz.y;
    xr = fmaxf(xr, 0.f);
    xi = fmaxf(xi, 0.f);
    if (last) {
      outp[(b * 2 + 0) * (long)(NN * NN) + rowoff + e] = xr;
      outp[(b * 2 + 1) * (long)(NN * NN) + rowoff + e] = xi;
    } else {
      float2 xo = xbuf[pbase + e];
      xbuf[pbase + e] = make_float2(xr, xi);
      ybuf[pbase + e] = make_float2(xr + beta * (xr - xo.x), xi + beta * (xi - xo.y));
    }
  }
}

// ---------------- mask permutation precompute (one-time) -------------------
// maskPT[b][sx][sy] = mask[b][P(sy)][P(sx)], P(s) = (s>>6) + 6*brev6(s&63)
__global__ __launch_bounds__(256) void k_mpre(const int* __restrict__ mask,
                                              unsigned char* __restrict__ maskPT) {
  long i = (long)blockIdx.x * 256 + threadIdx.x;
  long b = i / (NN * NN);
  int rem = (int)(i % (NN * NN));
  int sx = rem / NN, sy = rem % NN;
  int fx = (sx >> 6) + 6 * (int)(__brev((unsigned)(sx & 63)) >> 26);
  int fy = (sy >> 6) + 6 * (int)(__brev((unsigned)(sy & 63)) >> 26);
  maskPT[i] = (unsigned char)mask[b * (long)(NN * NN) + (long)fy * NN + fx];
}

// ---------------- precompute: cz = (1-lam)*cst + lam*z ---------------------
__global__ __launch_bounds__(256) void k_preA(const float* __restrict__ x0,
                                              const int* __restrict__ mask,
                                              float2* __restrict__ T) {
  __shared__ float2 U[4][LNPAD], V[4][LNPAD];
  int tid = threadIdx.x;
  int line = tid >> 6, t = tid & 63;
  long gl0 = (long)blockIdx.x * 4;
#pragma unroll
  for (int k = 0; k < 6; ++k) {
    int e = tid + k * 256; int l = e / NN; int x = e % NN;
    long gl = gl0 + l;
    long b = gl / NN;
    int y = (int)(gl % NN);
    long pidx = (long)y * NN + x;
    float mv = (float)mask[b * (long)(NN * NN) + pidx];
    float br = x0[(b * 2 + 0) * (long)(NN * NN) + pidx] * mv;
    float bi = x0[(b * 2 + 1) * (long)(NN * NN) + pidx] * mv;
    U[l][LID(x)] = make_float2(br, bi);
  }
  __syncthreads();
  fft384<1>(U[line], V[line], t);
#pragma unroll
  for (int k = 0; k < 6; ++k) {
    int e = tid + k * 256; int l = e / NN; int x = e % NN;
    float2 u = U[l][LID(x)];
    T[(gl0 + l) * NN + x] = make_float2(u.x * (1.0f / NN), u.y * (1.0f / NN));
  }
}

__global__ __launch_bounds__(256) void k_preB(const float2* __restrict__ T,
                                              float2* __restrict__ r0) {
  __shared__ float2 tile[NN][17];
  __shared__ float2 U[4][LNPAD], V[4][LNPAD];
  int tid = threadIdx.x;
  int xt = blockIdx.x % (NN / 16);
  long b = blockIdx.x / (NN / 16);
  int x0c = xt * 16;
  long sbase = b * (long)(NN * NN);
#pragma unroll
  for (int k = 0; k < 24; ++k) {
    int e = tid + k * 256; int y = e >> 4; int c = e & 15;
    tile[y][c] = T[sbase + (long)y * NN + x0c + c];
  }
  __syncthreads();
  int line = tid >> 6, t = tid & 63;
  for (int g = 0; g < 4; ++g) {
#pragma unroll
    for (int k = 0; k < 6; ++k) {
      int e = tid + k * 256; int l = e / NN; int y = e % NN;
      U[l][LID(y)] = tile[y][4 * g + l];
    }
    __syncthreads();
    fft384<1>(U[line], V[line], t);
#pragma unroll
    for (int k = 0; k < 6; ++k) {
      int e = tid + k * 256; int l = e / NN; int y = e % NN;
      float2 u = U[l][LID(y)];
      tile[y][4 * g + l] = make_float2(u.x * (1.0f / NN), u.y * (1.0f / NN));
    }
    __syncthreads();
  }
#pragma unroll
  for (int k = 0; k < 24; ++k) {
    int e = tid + k * 256; int y = e >> 4; int c = e & 15;
    r0[sbase + (long)y * NN + x0c + c] = tile[y][c];
  }
}

__global__ __launch_bounds__(256) void k_preC(const float* __restrict__ csm,
                                              const float2* __restrict__ r0,
                                              const float* __restrict__ zk,
                                              const float* __restrict__ lamp,
                                              float2* __restrict__ czb) {
  long i = (long)blockIdx.x * 256 + threadIdx.x;
  long b = i / (NN * NN);
  long p = i % (NN * NN);
  float sr = 0.f, si = 0.f;
#pragma unroll
  for (int c = 0; c < CC; ++c) {
    sr += csm[(b * 2 * CC + c) * (long)(NN * NN) + p];
    si -= csm[((b * 2 + 1) * CC + c) * (long)(NN * NN) + p];
  }
  float2 r = r0[i];
  float cstx = sr * r.x - si * r.y;
  float csty = sr * r.y + si * r.x;
  float lamv = lamp[0];
  float oml = 1.0f - lamv;
  float zr = zk[(b * 2 + 0) * (long)(NN * NN) + p];
  float zi = zk[(b * 2 + 1) * (long)(NN * NN) + p];
  czb[i] = make_float2(oml * cstx + lamv * zr, oml * csty + lamv * zi);
}

extern "C" void kernel_launch(void* const* d_in, const int* in_sizes, int n_in,
                              void* d_out, int out_size, void* d_ws, size_t ws_size,
                              hipStream_t stream) {
  const float* zk  = (const float*)d_in[0];
  const float* x0  = (const float*)d_in[1];
  const float* csm = (const float*)d_in[2];
  const float* lam = (const float*)d_in[3];
  const int*   msk = (const int*)d_in[4];
  float* out = (float*)d_out;

  // ws layout (float2 units): W1 [B*C*N*N] | y | x | cz | maskPT(uchar)
  size_t img = (size_t)BB * NN * NN;
  float2* W1   = (float2*)d_ws;
  float2* ybuf = W1 + (size_t)BB * CC * NN * NN;
  float2* xbuf = ybuf + img;
  float2* czb  = xbuf + img;
  unsigned char* maskPT = (unsigned char*)(czb + img);
  float2* T  = W1;        // precompute scratch overlays W1
  float2* r0 = W1 + img;

  double tcur = 1.0;
  float betas[NITER];
  for (int i = 0; i < NITER; ++i) {
    double tn = (1.0 + sqrt(1.0 + 4.0 * tcur * tcur)) * 0.5;
    betas[i] = (float)((tcur - 1.0) / tn);
    tcur = tn;
  }

  k_mpre<<<(BB * NN * NN) / 256, 256, 0, stream>>>(msk, maskPT);
  k_preA<<<BB * NN / 4, 256, 0, stream>>>(x0, msk, T);
  k_preB<<<BB * (NN / 16), 256, 0, stream>>>(T, r0);
  k_preC<<<(BB * NN * NN) / 256, 256, 0, stream>>>(csm, r0, zk, lam, czb);
  // iteration 1 (y0 = 0): x1 = prox(cz)
  k_e<<<(BB * NN * NN) / 256, 256, 0, stream>>>(czb, xbuf, ybuf);
  // iterations 2..20: forward, mask round-trip, adjoint+update
  for (int i = 1; i < NITER; ++i) {
    k_p1<<<BB * CC * NN / 4, 256, 0, stream>>>(ybuf, csm, W1);
    k_p2<<<BB * CC * (NN / 16), 256, 0, stream>>>(W1, maskPT);
    k_p3<<<BB * NN, 256, 0, stream>>>(W1, csm, czb, lam, xbuf, ybuf, out,
                                      betas[i], (i == NITER - 1) ? 1 : 0);
  }
}

// Round 16
// 1961.182 us; speedup vs baseline: 1.1496x; 1.1496x over previous
//
#include <hip/hip_runtime.h>
#include <math.h>

// FISTA data-consistency with masked multi-coil 2D FFT operator.
// B=4, C=16, H=W=384.
// Register FFT: 384 = 6 (regs) x 64 (lanes); DIF leaves bit-reversed-permuted
// frequencies; mask is pre-permuted; DIT consumes permuted order (free).
// Twiddles: 32-entry register table (1 sincosf/kernel) via __shfl, PRE-SIGNED.
// Exchanges (R16): h=1,2 DPP quad_perm; h=8 DPP row_ror:8 ((i+-8)%16 == i^8,
// rotation-direction-immune); h=4,16,32 __shfl_xor (LDS pipe). This cuts
// ds_bpermute count 25% — R14/R15 showed p2 at a VALU/LDS-pipe balance point
// (49us, both ~50%); only removing work from a pipe moves it.
// Butterflies: fma/fold (R13). P2: 8-col tile, 2 cols/wave (R15 lesson:
// 16-col/4-way ILP regressed — 4-way bank conflicts on fill + occupancy).
// zk folded out: cz=(1-lam)cst+lam*z; 1/N folded into wb chain.
// R3: don't fuse p3+p1. R8: fp16 W1 FAILS (range). R9: builtins only.
// R11: keep live ranges short. R14: permlane builtin = ~5 VALU ops (avoid).

#define NN 384
#define BB 4
#define CC 16
#define NITER 20
#define LNPAD 432   // old LDS path (precompute only)
#define PI_F 3.14159265358979323846f
#define TWOPI_F 6.28318530717958647692f

__device__ __forceinline__ int LID(int i) { return i + (i >> 3); }

__device__ __forceinline__ float2 cmulf(float2 a, float2 b) {
  return make_float2(a.x * b.x - a.y * b.y, a.x * b.y + a.y * b.x);
}

// ---------------- cross-lane exchange primitives ---------------------------
// DPP: quad_perm 0xB1 (xor-1), 0x4E (xor-2), row_ror:8 = 0x128 (xor-8 within
// 16-lane rows; (i+8)%16 == i^8 so rotation direction is irrelevant).
template<int CTRL>
__device__ __forceinline__ float dppx(float v) {
  int s = __float_as_int(v);
  return __int_as_float(__builtin_amdgcn_update_dpp(s, s, CTRL, 0xF, 0xF, true));
}

template<int H>
__device__ __forceinline__ float2 exch(float2 v) {
  if constexpr (H == 1) {
    return make_float2(dppx<0xB1>(v.x), dppx<0xB1>(v.y));   // quad [1,0,3,2]
  } else if constexpr (H == 2) {
    return make_float2(dppx<0x4E>(v.x), dppx<0x4E>(v.y));   // quad [2,3,0,1]
  } else if constexpr (H == 8) {
    return make_float2(dppx<0x128>(v.x), dppx<0x128>(v.y)); // row_ror:8
  } else {
    return make_float2(__shfl_xor(v.x, H), __shfl_xor(v.y, H));
  }
}

template<int DIR>
__device__ __forceinline__ void dft4(float2* v) {
  float ax = v[0].x + v[2].x, ay = v[0].y + v[2].y;
  float bx = v[0].x - v[2].x, by = v[0].y - v[2].y;
  float cx = v[1].x + v[3].x, cy = v[1].y + v[3].y;
  float dx = v[1].x - v[3].x, dy = v[1].y - v[3].y;
  float dix, diy;
  if (DIR < 0) { dix = dy; diy = -dx; }
  else         { dix = -dy; diy = dx; }
  v[0] = make_float2(ax + cx, ay + cy);
  v[2] = make_float2(ax - cx, ay - cy);
  v[1] = make_float2(bx + dix, by + diy);
  v[3] = make_float2(bx - dix, by - diy);
}

// DFT-3: X1 = m + i*s*S3*d, X2 = m - i*s*S3*d; m = a - u/2, u=b+c, d=b-c.
template<int SIGN>
__device__ __forceinline__ void dft3(float2 a, float2 b, float2 c,
                                     float2& X0, float2& X1, float2& X2) {
  const float S3 = 0.86602540378443864676f;
  float ux = b.x + c.x, uy = b.y + c.y;
  float dx = b.x - c.x, dy = b.y - c.y;
  float mx = a.x - 0.5f * ux, my = a.y - 0.5f * uy;
  float ex = S3 * dx, ey = S3 * dy;
  X0 = make_float2(a.x + ux, a.y + uy);
  if (SIGN < 0) {
    X1 = make_float2(mx + ey, my - ex);
    X2 = make_float2(mx - ey, my + ex);
  } else {
    X1 = make_float2(mx - ey, my + ex);
    X2 = make_float2(mx + ey, my - ex);
  }
}

// Fast DFT-6 = two DFT-3 + trivial W6 twiddles. Verified on impulses.
template<int SIGN>
__device__ __forceinline__ void dft6(float2* v) {
  const float S3 = 0.86602540378443864676f;
  float2 E0, E1, E2, O0, O1, O2;
  dft3<SIGN>(v[0], v[2], v[4], E0, E1, E2);
  dft3<SIGN>(v[1], v[3], v[5], O0, O1, O2);
  const float ss = (SIGN < 0) ? -S3 : S3;
  float2 T1 = cmulf(O1, make_float2(0.5f, ss));
  float2 T2 = cmulf(O2, make_float2(-0.5f, ss));
  v[0] = make_float2(E0.x + O0.x, E0.y + O0.y);
  v[1] = make_float2(E1.x + T1.x, E1.y + T1.y);
  v[2] = make_float2(E2.x + T2.x, E2.y + T2.y);
  v[3] = make_float2(E0.x - O0.x, E0.y - O0.y);
  v[4] = make_float2(E1.x - T1.x, E1.y - T1.y);
  v[5] = make_float2(E2.x - T2.x, E2.y - T2.y);
}

// ---------------- register FFT machinery (iteration path) ------------------
// fma/fold butterflies. Per stage (lane-hoisted): s = hi?-1:1,
// (csl,snl) = hi?(cs,sn):(1,0). Lo-lane cmul by (1,0) is exact.

// ---- single-column steps (p1) ----
template<int H>
__device__ __forceinline__ void dif_step1(float2 v[6], float s, float csl, float snl) {
#pragma unroll
  for (int r = 0; r < 6; ++r) {
    float2 o = exch<H>(v[r]);
    float dx = fmaf(s, v[r].x, o.x);
    float dy = fmaf(s, v[r].y, o.y);
    v[r] = make_float2(dx * csl - dy * snl, dx * snl + dy * csl);
  }
}
template<int H>
__device__ __forceinline__ void dif_step1_notw(float2 v[6], float s) {
#pragma unroll
  for (int r = 0; r < 6; ++r) {
    float2 o = exch<H>(v[r]);
    v[r] = make_float2(fmaf(s, v[r].x, o.x), fmaf(s, v[r].y, o.y));
  }
}
template<int H>
__device__ __forceinline__ void dif_step2(float2 u[6], float2 v[6],
                                          float s, float csl, float snl) {
#pragma unroll
  for (int r = 0; r < 6; ++r) {
    float2 ou = exch<H>(u[r]);
    float2 ov = exch<H>(v[r]);
    float dux = fmaf(s, u[r].x, ou.x), duy = fmaf(s, u[r].y, ou.y);
    float dvx = fmaf(s, v[r].x, ov.x), dvy = fmaf(s, v[r].y, ov.y);
    u[r] = make_float2(dux * csl - duy * snl, dux * snl + duy * csl);
    v[r] = make_float2(dvx * csl - dvy * snl, dvx * snl + dvy * csl);
  }
}
template<int H>
__device__ __forceinline__ void dif_step2_notw(float2 u[6], float2 v[6], float s) {
#pragma unroll
  for (int r = 0; r < 6; ++r) {
    float2 ou = exch<H>(u[r]);
    float2 ov = exch<H>(v[r]);
    u[r] = make_float2(fmaf(s, u[r].x, ou.x), fmaf(s, u[r].y, ou.y));
    v[r] = make_float2(fmaf(s, v[r].x, ov.x), fmaf(s, v[r].y, ov.y));
  }
}

// dit: bt = cmul(v, tw'); v' = fma(s, bt, exch(bt))
template<int H>
__device__ __forceinline__ void dit_step2(float2 u[6], float2 v[6],
                                          float s, float csl, float snl) {
#pragma unroll
  for (int r = 0; r < 6; ++r) {
    float2 bu = make_float2(u[r].x * csl - u[r].y * snl, u[r].x * snl + u[r].y * csl);
    float2 bv = make_float2(v[r].x * csl - v[r].y * snl, v[r].x * snl + v[r].y * csl);
    float2 ou = exch<H>(bu);
    float2 ov = exch<H>(bv);
    u[r] = make_float2(fmaf(s, bu.x, ou.x), fmaf(s, bu.y, ou.y));
    v[r] = make_float2(fmaf(s, bv.x, ov.x), fmaf(s, bv.y, ov.y));
  }
}
template<int H>
__device__ __forceinline__ void dit_step2_notw(float2 u[6], float2 v[6], float s) {
#pragma unroll
  for (int r = 0; r < 6; ++r) {
    float2 ou = exch<H>(u[r]);
    float2 ov = exch<H>(v[r]);
    u[r] = make_float2(fmaf(s, u[r].x, ou.x), fmaf(s, u[r].y, ou.y));
    v[r] = make_float2(fmaf(s, v[r].x, ov.x), fmaf(s, v[r].y, ov.y));
  }
}

// ---- DIF drivers ----
template<int SIGN>
__device__ __forceinline__ void dif64t(float2 v[6], int t, float tc, float tss) {
  { int j = t & 31; bool hi = (t & 32) != 0;
    float cs = __shfl(tc, j), sn = __shfl(tss, j);
    float s = hi ? -1.f : 1.f, csl = hi ? cs : 1.f, snl = hi ? sn : 0.f;
    dif_step1<32>(v, s, csl, snl); }
  { int j = (t & 15) << 1; bool hi = (t & 16) != 0;
    float cs = __shfl(tc, j), sn = __shfl(tss, j);
    float s = hi ? -1.f : 1.f, csl = hi ? cs : 1.f, snl = hi ? sn : 0.f;
    dif_step1<16>(v, s, csl, snl); }
  { int j = (t & 7) << 2; bool hi = (t & 8) != 0;
    float cs = __shfl(tc, j), sn = __shfl(tss, j);
    float s = hi ? -1.f : 1.f, csl = hi ? cs : 1.f, snl = hi ? sn : 0.f;
    dif_step1<8>(v, s, csl, snl); }
  { int j = (t & 3) << 3; bool hi = (t & 4) != 0;
    float cs = __shfl(tc, j), sn = __shfl(tss, j);
    float s = hi ? -1.f : 1.f, csl = hi ? cs : 1.f, snl = hi ? sn : 0.f;
    dif_step1<4>(v, s, csl, snl); }
  { bool hi = (t & 2) != 0, iq = (t & 1) != 0;
    float s = hi ? -1.f : 1.f;
    float c2 = (hi && iq) ? 0.f : 1.f;
    float s2 = (hi && iq) ? (float)SIGN : 0.f;
    dif_step1<2>(v, s, c2, s2); }
  { bool hi = (t & 1) != 0;
    float s = hi ? -1.f : 1.f;
    dif_step1_notw<1>(v, s); }
}

template<int SIGN>
__device__ __forceinline__ void dif64t2(float2 u[6], float2 v[6], int t,
                                        float tc, float tss) {
  { int j = t & 31; bool hi = (t & 32) != 0;                  // h=32 (shfl)
    float cs = __shfl(tc, j), sn = __shfl(tss, j);
    float s = hi ? -1.f : 1.f, csl = hi ? cs : 1.f, snl = hi ? sn : 0.f;
    dif_step2<32>(u, v, s, csl, snl); }
  { int j = (t & 15) << 1; bool hi = (t & 16) != 0;           // h=16 (shfl)
    float cs = __shfl(tc, j), sn = __shfl(tss, j);
    float s = hi ? -1.f : 1.f, csl = hi ? cs : 1.f, snl = hi ? sn : 0.f;
    dif_step2<16>(u, v, s, csl, snl); }
  { int j = (t & 7) << 2; bool hi = (t & 8) != 0;             // h=8 (DPP ror)
    float cs = __shfl(tc, j), sn = __shfl(tss, j);
    float s = hi ? -1.f : 1.f, csl = hi ? cs : 1.f, snl = hi ? sn : 0.f;
    dif_step2<8>(u, v, s, csl, snl); }
  { int j = (t & 3) << 3; bool hi = (t & 4) != 0;             // h=4 (shfl)
    float cs = __shfl(tc, j), sn = __shfl(tss, j);
    float s = hi ? -1.f : 1.f, csl = hi ? cs : 1.f, snl = hi ? sn : 0.f;
    dif_step2<4>(u, v, s, csl, snl); }
  { bool hi = (t & 2) != 0, iq = (t & 1) != 0;                // h=2 (DPP)
    float s = hi ? -1.f : 1.f;
    float c2 = (hi && iq) ? 0.f : 1.f;
    float s2 = (hi && iq) ? (float)SIGN : 0.f;
    dif_step2<2>(u, v, s, c2, s2); }
  { bool hi = (t & 1) != 0;                                   // h=1 (DPP, tw=1)
    float s = hi ? -1.f : 1.f;
    dif_step2_notw<1>(u, v, s); }
}

// ---- DIT drivers ----
template<int SIGN>
__device__ __forceinline__ void dit64t2(float2 u[6], float2 v[6], int t,
                                        float tc, float tss) {
  { bool hi = (t & 1) != 0;                                   // h=1 (DPP, tw=1)
    float s = hi ? -1.f : 1.f;
    dit_step2_notw<1>(u, v, s); }
  { bool hi = (t & 2) != 0, iq = (t & 1) != 0;                // h=2 (DPP)
    float s = hi ? -1.f : 1.f;
    float c2 = (hi && iq) ? 0.f : 1.f;
    float s2 = (hi && iq) ? (float)SIGN : 0.f;
    dit_step2<2>(u, v, s, c2, s2); }
  { int j = (t & 3) << 3; bool hi = (t & 4) != 0;             // h=4 (shfl)
    float cs = __shfl(tc, j), sn = __shfl(tss, j);
    float s = hi ? -1.f : 1.f, csl = hi ? cs : 1.f, snl = hi ? sn : 0.f;
    dit_step2<4>(u, v, s, csl, snl); }
  { int j = (t & 7) << 2; bool hi = (t & 8) != 0;             // h=8 (DPP ror)
    float cs = __shfl(tc, j), sn = __shfl(tss, j);
    float s = hi ? -1.f : 1.f, csl = hi ? cs : 1.f, snl = hi ? sn : 0.f;
    dit_step2<8>(u, v, s, csl, snl); }
  { int j = (t & 15) << 1; bool hi = (t & 16) != 0;           // h=16 (shfl)
    float cs = __shfl(tc, j), sn = __shfl(tss, j);
    float s = hi ? -1.f : 1.f, csl = hi ? cs : 1.f, snl = hi ? sn : 0.f;
    dit_step2<16>(u, v, s, csl, snl); }
  { int j = t & 31; bool hi = (t & 32) != 0;                  // h=32 (shfl)
    float cs = __shfl(tc, j), sn = __shfl(tss, j);
    float s = hi ? -1.f : 1.f, csl = hi ? cs : 1.f, snl = hi ? sn : 0.f;
    dit_step2<32>(u, v, s, csl, snl); }
}

// FWD single: natural in -> permuted out. w[r-1] = exp(SIGN*2pi*i*r*t/384).
template<int SIGN>
__device__ __forceinline__ void fwd384t(float2 v[6], int t, float tc, float tss,
                                        const float2 w[5]) {
  dft6<SIGN>(v);
#pragma unroll
  for (int r = 1; r < 6; ++r) v[r] = cmulf(v[r], w[r - 1]);
  dif64t<SIGN>(v, t, tc, tss);
}

// FWD dual
template<int SIGN>
__device__ __forceinline__ void fwd384t2(float2 u[6], float2 v[6], int t,
                                         float tc, float tss, const float2 w[5]) {
  dft6<SIGN>(u);
  dft6<SIGN>(v);
#pragma unroll
  for (int r = 1; r < 6; ++r) { u[r] = cmulf(u[r], w[r - 1]); v[r] = cmulf(v[r], w[r - 1]); }
  dif64t2<SIGN>(u, v, t, tc, tss);
}

// BWD dual: permuted in -> natural out; sc0 scales the r=0 term.
template<int SIGN>
__device__ __forceinline__ void bwd384t2(float2 u[6], float2 v[6], int t,
                                         float tc, float tss, const float2 w[5],
                                         float sc0) {
  dit64t2<SIGN>(u, v, t, tc, tss);
  u[0].x *= sc0; u[0].y *= sc0;
  v[0].x *= sc0; v[0].y *= sc0;
#pragma unroll
  for (int r = 1; r < 6; ++r) { u[r] = cmulf(u[r], w[r - 1]); v[r] = cmulf(v[r], w[r - 1]); }
  dft6<SIGN>(u);
  dft6<SIGN>(v);
}

// ---------------- old LDS fft384 (precompute kernels only) -----------------
template<int R, int NS, int DIR>
__device__ __forceinline__ void fft_stage(const float2* S, float2* D, int t) {
  constexpr int NR = NN / R;
#pragma unroll
  for (int rep = 0; rep < (NR + 63) / 64; ++rep) {
    int j = t + rep * 64;
    if (j < NR) {
      float2 v[R];
#pragma unroll
      for (int r = 0; r < R; ++r) v[r] = S[LID(j + r * NR)];
      if constexpr (NS > 1) {
        float ang = (float)DIR * (TWOPI_F / (float)(NS * R)) * (float)(j % NS);
        float sv, cv;
        __sincosf(ang, &sv, &cv);
        float2 w = make_float2(cv, sv);
        float2 wr = w;
#pragma unroll
        for (int r = 1; r < R; ++r) { v[r] = cmulf(v[r], wr); wr = cmulf(wr, w); }
      }
      if constexpr (R == 4) dft4<DIR>(v); else dft6<DIR>(v);
      int base = (j / NS) * (NS * R) + (j % NS);
#pragma unroll
      for (int r = 0; r < R; ++r) D[LID(base + r * NS)] = v[r];
    }
  }
}

template<int DIR>
__device__ __forceinline__ void fft384(float2* A, float2* Bf, int t) {
  fft_stage<4, 1,  DIR>(A,  Bf, t); __syncthreads();
  fft_stage<4, 4,  DIR>(Bf, A,  t); __syncthreads();
  fft_stage<4, 16, DIR>(A,  Bf, t); __syncthreads();
  fft_stage<6, 64, DIR>(Bf, A,  t); __syncthreads();
}

// ---------------- E: iteration 1 (y0 = 0 -> xn = cz), elementwise ----------
__global__ __launch_bounds__(256) void k_e(const float2* __restrict__ czb,
                                           float2* __restrict__ xbuf,
                                           float2* __restrict__ ybuf) {
  long i = (long)blockIdx.x * 256 + threadIdx.x;
  float2 cz = czb[i];
  float2 x = make_float2(fmaxf(cz.x, 0.f), fmaxf(cz.y, 0.f));
  xbuf[i] = x;
  ybuf[i] = x;   // t1 = 1 -> y1 = x1
}

// ---------------- P1: row FFT of coil*y -> W1 (permuted-x storage) ---------
// grid B*C*384/4, 256 thr; one wave per row; no LDS, no barriers.
__global__ __launch_bounds__(256) void k_p1(const float2* __restrict__ ybuf,
                                            const float* __restrict__ csm,
                                            float2* __restrict__ W1) {
  int t = threadIdx.x & 63;
  int w = threadIdx.x >> 6;
  long gl = (long)blockIdx.x * 4 + w;       // (b*C + c)*384 + y
  int y = (int)(gl % NN);
  long bc = gl / NN;
  long b = bc >> 4, c = bc & 15;
  long rowoff = (long)y * NN;
  float tc, ts; __sincosf((float)(t & 31) * (PI_F / 32.0f), &ts, &tc);
  float tsf = -ts;                           // fwd (SIGN=-1) pre-signed
  float2 w0; __sincosf(-(float)t * (TWOPI_F / 384.0f), &w0.y, &w0.x);
  float2 wf[5];
  wf[0] = w0;
#pragma unroll
  for (int r = 1; r < 5; ++r) wf[r] = cmulf(wf[r - 1], w0);
  const float2* yrow = ybuf + b * (long)(NN * NN) + rowoff;
  const float* crow_re = csm + (b * 2 * CC + c) * (long)(NN * NN) + rowoff;
  const float* crow_im = crow_re + (long)CC * NN * NN;
  float2 v[6];
#pragma unroll
  for (int k = 0; k < 6; ++k) {
    int x = t + 64 * k;
    float2 yv = yrow[x];
    float cre = crow_re[x], cim = crow_im[x];
    v[k] = make_float2(yv.x * cre - yv.y * cim, yv.x * cim + yv.y * cre);
  }
  fwd384t<-1>(v, t, tc, tsf, wf);
  float2* orow = W1 + gl * NN;
#pragma unroll
  for (int r = 0; r < 6; ++r) orow[t + 64 * r] = v[r];
}

// ---------------- P2: col FFT -> mask -> col IFFT, in-place on W1 ----------
// grid B*C*(N/8)=3072 blocks, 256 thr. 8-col planar tile, pad 392.
// float4 fill/drain; each wave runs cols {2w, 2w+1} interleaved through one
// FFT body. XCD-chunked swizzle (R6). 1/N folded into wb + sc0.
#define P2PAD 392
__global__ __launch_bounds__(256) void k_p2(float2* __restrict__ W1,
                                            const unsigned char* __restrict__ maskPT) {
  __shared__ float ldsR[8][P2PAD];
  __shared__ float ldsI[8][P2PAD];
  int tid = threadIdx.x;
  const int nwg = BB * CC * (NN / 8);            // 3072, divisible by 8
  int l = ((int)blockIdx.x & 7) * (nwg >> 3) + ((int)blockIdx.x >> 3);
  int xt = l % (NN / 8);
  long bc = l / (NN / 8);
  long b = bc >> 4;
  int s0 = xt * 8;
  long sbase = bc * (long)(NN * NN);
  int w = tid >> 6, t = tid & 63;
  // twiddle setup: table (pre-signed per direction) + outer chains
  float tc, ts; __sincosf((float)(t & 31) * (PI_F / 32.0f), &ts, &tc);
  float tsf = -ts;
  float2 w0; __sincosf(-(float)t * (TWOPI_F / 384.0f), &w0.y, &w0.x);
  float2 wf[5], wb[5];
  wf[0] = w0;
#pragma unroll
  for (int r = 1; r < 5; ++r) wf[r] = cmulf(wf[r - 1], w0);
  const float inv = 1.0f / NN;
#pragma unroll
  for (int r = 0; r < 5; ++r) wb[r] = make_float2(wf[r].x * inv, -wf[r].y * inv);
  // fill: float4 (2 complex) per op; 6 ops/thread
  const float4* W1v = (const float4*)W1;
  long f4base = (sbase >> 1) + (s0 >> 1);
#pragma unroll
  for (int k = 0; k < 6; ++k) {
    int e = tid + k * 256; int y = e >> 2; int q = e & 3;
    float4 val = W1v[f4base + (long)y * (NN / 2) + q];
    ldsR[2 * q][y] = val.x; ldsI[2 * q][y] = val.y;
    ldsR[2 * q + 1][y] = val.z; ldsI[2 * q + 1][y] = val.w;
  }
  __syncthreads();
  const unsigned char* mb = maskPT + b * (long)(NN * NN);
  {
    int c0 = 2 * w, c1 = 2 * w + 1;
    float2 u[6], v[6];
#pragma unroll
    for (int k = 0; k < 6; ++k) {
      u[k] = make_float2(ldsR[c0][t + 64 * k], ldsI[c0][t + 64 * k]);
      v[k] = make_float2(ldsR[c1][t + 64 * k], ldsI[c1][t + 64 * k]);
    }
    fwd384t2<-1>(u, v, t, tc, tsf, wf);
    const unsigned char* m0 = mb + (long)(s0 + c0) * NN;
    const unsigned char* m1 = mb + (long)(s0 + c1) * NN;
#pragma unroll
    for (int r = 0; r < 6; ++r) {
      float mv0 = (float)m0[t + 64 * r];
      float mv1 = (float)m1[t + 64 * r];
      u[r].x *= mv0; u[r].y *= mv0;
      v[r].x *= mv1; v[r].y *= mv1;
    }
    bwd384t2<1>(u, v, t, tc, ts, wb, inv);
#pragma unroll
    for (int k = 0; k < 6; ++k) {
      ldsR[c0][t + 64 * k] = u[k].x;
      ldsI[c0][t + 64 * k] = u[k].y;
      ldsR[c1][t + 64 * k] = v[k].x;
      ldsI[c1][t + 64 * k] = v[k].y;
    }
  }
  __syncthreads();
  float4* W1o = (float4*)W1;
#pragma unroll
  for (int k = 0; k < 6; ++k) {
    int e = tid + k * 256; int y = e >> 2; int q = e & 3;
    float4 val;
    val.x = ldsR[2 * q][y]; val.y = ldsI[2 * q][y];
    val.z = ldsR[2 * q + 1][y]; val.w = ldsI[2 * q + 1][y];
    W1o[f4base + (long)y * (NN / 2) + q] = val;
  }
}

// ---------------- P3: row IFFT + conj(coil) reduce + FISTA update ----------
// grid B*384 blocks, 256 thr; wave w handles coils 4w..4w+3 (2 at a time);
// LDS reduce. Update: x = prox((1-lam)(y - Q) + cz); zk not touched.
// last!=0: write planar output instead of x/y (final iteration).
__global__ __launch_bounds__(256) void k_p3(const float2* __restrict__ W1,
                                            const float* __restrict__ csm,
                                            const float2* __restrict__ czb,
                                            const float* __restrict__ lamp,
                                            float2* __restrict__ xbuf,
                                            float2* __restrict__ ybuf,
                                            float* __restrict__ outp,
                                            float beta, int last) {
  __shared__ float2 part[4][NN];
  int tid = threadIdx.x;
  int w = tid >> 6, t = tid & 63;
  long gl = blockIdx.x;            // b*384 + y
  long b = gl / NN;
  int y = (int)(gl % NN);
  long rowoff = (long)y * NN;
  float tc, ts; __sincosf((float)(t & 31) * (PI_F / 32.0f), &ts, &tc);
  float2 w0; __sincosf((float)t * (TWOPI_F / 384.0f), &w0.y, &w0.x);
  float2 wb[5];
  wb[0] = w0;
#pragma unroll
  for (int r = 1; r < 5; ++r) wb[r] = cmulf(wb[r - 1], w0);
  float2 acc[6];
#pragma unroll
  for (int k = 0; k < 6; ++k) acc[k] = make_float2(0.f, 0.f);
#pragma unroll
  for (int ci = 0; ci < 4; ci += 2) {
    int c0 = w * 4 + ci, c1 = c0 + 1;
    const float2* row0 = W1 + ((b * CC + c0) * (long)NN + y) * NN;
    const float2* row1 = W1 + ((b * CC + c1) * (long)NN + y) * NN;
    float2 u[6], v[6];
#pragma unroll
    for (int r = 0; r < 6; ++r) { u[r] = row0[t + 64 * r]; v[r] = row1[t + 64 * r]; }
    bwd384t2<1>(u, v, t, tc, ts, wb, 1.0f);
    const float* cre0 = csm + (b * 2 * CC + c0) * (long)(NN * NN) + rowoff;
    const float* cim0 = cre0 + (long)CC * NN * NN;
    const float* cre1 = csm + (b * 2 * CC + c1) * (long)(NN * NN) + rowoff;
    const float* cim1 = cre1 + (long)CC * NN * NN;
#pragma unroll
    for (int k = 0; k < 6; ++k) {
      int x = t + 64 * k;
      float a0 = cre0[x], b0 = cim0[x];
      float a1 = cre1[x], b1 = cim1[x];
      acc[k].x += (a0 * u[k].x + b0 * u[k].y) + (a1 * v[k].x + b1 * v[k].y);
      acc[k].y += (a0 * u[k].y - b0 * u[k].x) + (a1 * v[k].y - b1 * v[k].x);
    }
  }
#pragma unroll
  for (int k = 0; k < 6; ++k) part[w][t + 64 * k] = acc[k];
  __syncthreads();
  float lamv = lamp[0];
  float oml = 1.0f - lamv;
  long pbase = b * (long)(NN * NN) + rowoff;
  for (int e = tid; e < NN; e += 256) {
    float Qx = (part[0][e].x + part[1][e].x + part[2][e].x + part[3][e].x) * (1.0f / NN);
    float Qy = (part[0][e].y + part[1][e].y + part[2][e].y + part[3][e].y) * (1.0f / NN);
    float2 yv = ybuf[pbase + e];
    float2 cz = czb[pbase + e];
    float xr = oml * (yv.x - Qx) + cz.x;
    float xi = oml * (yv.y - Qy) + cz.y;
    xr = fmaxf(xr, 0.f);
    xi = fmaxf(xi, 0.f);
    if (last) {
      outp[(b * 2 + 0) * (long)(NN * NN) + rowoff + e] = xr;
      outp[(b * 2 + 1) * (long)(NN * NN) + rowoff + e] = xi;
    } else {
      float2 xo = xbuf[pbase + e];
      xbuf[pbase + e] = make_float2(xr, xi);
      ybuf[pbase + e] = make_float2(xr + beta * (xr - xo.x), xi + beta * (xi - xo.y));
    }
  }
}

// ---------------- mask permutation precompute (one-time) -------------------
// maskPT[b][sx][sy] = mask[b][P(sy)][P(sx)], P(s) = (s>>6) + 6*brev6(s&63)
__global__ __launch_bounds__(256) void k_mpre(const int* __restrict__ mask,
                                              unsigned char* __restrict__ maskPT) {
  long i = (long)blockIdx.x * 256 + threadIdx.x;
  long b = i / (NN * NN);
  int rem = (int)(i % (NN * NN));
  int sx = rem / NN, sy = rem % NN;
  int fx = (sx >> 6) + 6 * (int)(__brev((unsigned)(sx & 63)) >> 26);
  int fy = (sy >> 6) + 6 * (int)(__brev((unsigned)(sy & 63)) >> 26);
  maskPT[i] = (unsigned char)mask[b * (long)(NN * NN) + (long)fy * NN + fx];
}

// ---------------- precompute: cz = (1-lam)*cst + lam*z ---------------------
__global__ __launch_bounds__(256) void k_preA(const float* __restrict__ x0,
                                              const int* __restrict__ mask,
                                              float2* __restrict__ T) {
  __shared__ float2 U[4][LNPAD], V[4][LNPAD];
  int tid = threadIdx.x;
  int line = tid >> 6, t = tid & 63;
  long gl0 = (long)blockIdx.x * 4;
#pragma unroll
  for (int k = 0; k < 6; ++k) {
    int e = tid + k * 256; int l = e / NN; int x = e % NN;
    long gl = gl0 + l;
    long b = gl / NN;
    int y = (int)(gl % NN);
    long pidx = (long)y * NN + x;
    float mv = (float)mask[b * (long)(NN * NN) + pidx];
    float br = x0[(b * 2 + 0) * (long)(NN * NN) + pidx] * mv;
    float bi = x0[(b * 2 + 1) * (long)(NN * NN) + pidx] * mv;
    U[l][LID(x)] = make_float2(br, bi);
  }
  __syncthreads();
  fft384<1>(U[line], V[line], t);
#pragma unroll
  for (int k = 0; k < 6; ++k) {
    int e = tid + k * 256; int l = e / NN; int x = e % NN;
    float2 u = U[l][LID(x)];
    T[(gl0 + l) * NN + x] = make_float2(u.x * (1.0f / NN), u.y * (1.0f / NN));
  }
}

__global__ __launch_bounds__(256) void k_preB(const float2* __restrict__ T,
                                              float2* __restrict__ r0) {
  __shared__ float2 tile[NN][17];
  __shared__ float2 U[4][LNPAD], V[4][LNPAD];
  int tid = threadIdx.x;
  int xt = blockIdx.x % (NN / 16);
  long b = blockIdx.x / (NN / 16);
  int x0c = xt * 16;
  long sbase = b * (long)(NN * NN);
#pragma unroll
  for (int k = 0; k < 24; ++k) {
    int e = tid + k * 256; int y = e >> 4; int c = e & 15;
    tile[y][c] = T[sbase + (long)y * NN + x0c + c];
  }
  __syncthreads();
  int line = tid >> 6, t = tid & 63;
  for (int g = 0; g < 4; ++g) {
#pragma unroll
    for (int k = 0; k < 6; ++k) {
      int e = tid + k * 256; int l = e / NN; int y = e % NN;
      U[l][LID(y)] = tile[y][4 * g + l];
    }
    __syncthreads();
    fft384<1>(U[line], V[line], t);
#pragma unroll
    for (int k = 0; k < 6; ++k) {
      int e = tid + k * 256; int l = e / NN; int y = e % NN;
      float2 u = U[l][LID(y)];
      tile[y][4 * g + l] = make_float2(u.x * (1.0f / NN), u.y * (1.0f / NN));
    }
    __syncthreads();
  }
#pragma unroll
  for (int k = 0; k < 24; ++k) {
    int e = tid + k * 256; int y = e >> 4; int c = e & 15;
    r0[sbase + (long)y * NN + x0c + c] = tile[y][c];
  }
}

__global__ __launch_bounds__(256) void k_preC(const float* __restrict__ csm,
                                              const float2* __restrict__ r0,
                                              const float* __restrict__ zk,
                                              const float* __restrict__ lamp,
                                              float2* __restrict__ czb) {
  long i = (long)blockIdx.x * 256 + threadIdx.x;
  long b = i / (NN * NN);
  long p = i % (NN * NN);
  float sr = 0.f, si = 0.f;
#pragma unroll
  for (int c = 0; c < CC; ++c) {
    sr += csm[(b * 2 * CC + c) * (long)(NN * NN) + p];
    si -= csm[((b * 2 + 1) * CC + c) * (long)(NN * NN) + p];
  }
  float2 r = r0[i];
  float cstx = sr * r.x - si * r.y;
  float csty = sr * r.y + si * r.x;
  float lamv = lamp[0];
  float oml = 1.0f - lamv;
  float zr = zk[(b * 2 + 0) * (long)(NN * NN) + p];
  float zi = zk[(b * 2 + 1) * (long)(NN * NN) + p];
  czb[i] = make_float2(oml * cstx + lamv * zr, oml * csty + lamv * zi);
}

extern "C" void kernel_launch(void* const* d_in, const int* in_sizes, int n_in,
                              void* d_out, int out_size, void* d_ws, size_t ws_size,
                              hipStream_t stream) {
  const float* zk  = (const float*)d_in[0];
  const float* x0  = (const float*)d_in[1];
  const float* csm = (const float*)d_in[2];
  const float* lam = (const float*)d_in[3];
  const int*   msk = (const int*)d_in[4];
  float* out = (float*)d_out;

  // ws layout (float2 units): W1 [B*C*N*N] | y | x | cz | maskPT(uchar)
  size_t img = (size_t)BB * NN * NN;
  float2* W1   = (float2*)d_ws;
  float2* ybuf = W1 + (size_t)BB * CC * NN * NN;
  float2* xbuf = ybuf + img;
  float2* czb  = xbuf + img;
  unsigned char* maskPT = (unsigned char*)(czb + img);
  float2* T  = W1;        // precompute scratch overlays W1
  float2* r0 = W1 + img;

  double tcur = 1.0;
  float betas[NITER];
  for (int i = 0; i < NITER; ++i) {
    double tn = (1.0 + sqrt(1.0 + 4.0 * tcur * tcur)) * 0.5;
    betas[i] = (float)((tcur - 1.0) / tn);
    tcur = tn;
  }

  k_mpre<<<(BB * NN * NN) / 256, 256, 0, stream>>>(msk, maskPT);
  k_preA<<<BB * NN / 4, 256, 0, stream>>>(x0, msk, T);
  k_preB<<<BB * (NN / 16), 256, 0, stream>>>(T, r0);
  k_preC<<<(BB * NN * NN) / 256, 256, 0, stream>>>(csm, r0, zk, lam, czb);
  // iteration 1 (y0 = 0): x1 = prox(cz)
  k_e<<<(BB * NN * NN) / 256, 256, 0, stream>>>(czb, xbuf, ybuf);
  // iterations 2..20: forward, mask round-trip, adjoint+update
  for (int i = 1; i < NITER; ++i) {
    k_p1<<<BB * CC * NN / 4, 256, 0, stream>>>(ybuf, csm, W1);
    k_p2<<<BB * CC * (NN / 8), 256, 0, stream>>>(W1, maskPT);
    k_p3<<<BB * NN, 256, 0, stream>>>(W1, csm, czb, lam, xbuf, ybuf, out,
                                      betas[i], (i == NITER - 1) ? 1 : 0);
  }
}

// Round 17
// 1885.302 us; speedup vs baseline: 1.1959x; 1.0402x over previous
//
#include <hip/hip_runtime.h>
#include <math.h>

// FISTA data-consistency with masked multi-coil 2D FFT operator.
// B=4, C=16, H=W=384.
// p1/p3: register FFT 384 = 6 regs x 64 lanes (R16 form, verified).
// p2 (R17): 384 = 24 regs x 16 lanes — lane-FFT-16 stages h=8(DPP ror),
// h=4(shfl, the ONLY LDS-pipe stage), h=2,1(DPP quad). LDS-pipe ops/col
// drop 3x vs R16 (R16 measured: p2 time ~linear in ds_bpermute load).
// DFT-24 per lane = 4x dft6 + W24-constant twiddles + 6x dft4.
// Mask: y-freq at (t16,k1) = k1 + 24*brev4(t16) computed in-kernel;
// maskPT permutes x only. p2 absmax NOT bit-exact (new factorization).
// Twiddles: 32-entry table via __shfl (pre-signed); W384^{t*k1} via P/Q
// power decomposition (low chain depth).
// R3: don't fuse p3+p1. R8: fp16 W1 FAILS (range). R9: builtins only.
// R11: short live ranges. R14: permlane builtin ~5 VALU ops (avoid).
// R15: 4-col ILP regressed (bank conflicts + occupancy).

#define NN 384
#define BB 4
#define CC 16
#define NITER 20
#define LNPAD 432   // old LDS path (precompute only)
#define PI_F 3.14159265358979323846f
#define TWOPI_F 6.28318530717958647692f

__device__ __forceinline__ int LID(int i) { return i + (i >> 3); }

__device__ __forceinline__ float2 cmulf(float2 a, float2 b) {
  return make_float2(a.x * b.x - a.y * b.y, a.x * b.y + a.y * b.x);
}

// ---------------- cross-lane exchange primitives ---------------------------
// DPP: quad_perm 0xB1 (xor-1), 0x4E (xor-2), row_ror:8 = 0x128 (xor-8 within
// 16-lane rows; (i+-8)%16 == i^8). All HW-verified bit-exact (R12/R16).
template<int CTRL>
__device__ __forceinline__ float dppx(float v) {
  int s = __float_as_int(v);
  return __int_as_float(__builtin_amdgcn_update_dpp(s, s, CTRL, 0xF, 0xF, true));
}

template<int H>
__device__ __forceinline__ float2 exch(float2 v) {
  if constexpr (H == 1) {
    return make_float2(dppx<0xB1>(v.x), dppx<0xB1>(v.y));   // quad [1,0,3,2]
  } else if constexpr (H == 2) {
    return make_float2(dppx<0x4E>(v.x), dppx<0x4E>(v.y));   // quad [2,3,0,1]
  } else if constexpr (H == 8) {
    return make_float2(dppx<0x128>(v.x), dppx<0x128>(v.y)); // row_ror:8
  } else {
    return make_float2(__shfl_xor(v.x, H), __shfl_xor(v.y, H));
  }
}

template<int DIR>
__device__ __forceinline__ void dft4(float2* v) {
  float ax = v[0].x + v[2].x, ay = v[0].y + v[2].y;
  float bx = v[0].x - v[2].x, by = v[0].y - v[2].y;
  float cx = v[1].x + v[3].x, cy = v[1].y + v[3].y;
  float dx = v[1].x - v[3].x, dy = v[1].y - v[3].y;
  float dix, diy;
  if (DIR < 0) { dix = dy; diy = -dx; }
  else         { dix = -dy; diy = dx; }
  v[0] = make_float2(ax + cx, ay + cy);
  v[2] = make_float2(ax - cx, ay - cy);
  v[1] = make_float2(bx + dix, by + diy);
  v[3] = make_float2(bx - dix, by - diy);
}

// DFT-3: X1 = m + i*s*S3*d, X2 = m - i*s*S3*d; m = a - u/2, u=b+c, d=b-c.
template<int SIGN>
__device__ __forceinline__ void dft3(float2 a, float2 b, float2 c,
                                     float2& X0, float2& X1, float2& X2) {
  const float S3 = 0.86602540378443864676f;
  float ux = b.x + c.x, uy = b.y + c.y;
  float dx = b.x - c.x, dy = b.y - c.y;
  float mx = a.x - 0.5f * ux, my = a.y - 0.5f * uy;
  float ex = S3 * dx, ey = S3 * dy;
  X0 = make_float2(a.x + ux, a.y + uy);
  if (SIGN < 0) {
    X1 = make_float2(mx + ey, my - ex);
    X2 = make_float2(mx - ey, my + ex);
  } else {
    X1 = make_float2(mx - ey, my + ex);
    X2 = make_float2(mx + ey, my - ex);
  }
}

// Fast DFT-6 = two DFT-3 + trivial W6 twiddles. Verified on impulses.
template<int SIGN>
__device__ __forceinline__ void dft6(float2* v) {
  const float S3 = 0.86602540378443864676f;
  float2 E0, E1, E2, O0, O1, O2;
  dft3<SIGN>(v[0], v[2], v[4], E0, E1, E2);
  dft3<SIGN>(v[1], v[3], v[5], O0, O1, O2);
  const float ss = (SIGN < 0) ? -S3 : S3;
  float2 T1 = cmulf(O1, make_float2(0.5f, ss));
  float2 T2 = cmulf(O2, make_float2(-0.5f, ss));
  v[0] = make_float2(E0.x + O0.x, E0.y + O0.y);
  v[1] = make_float2(E1.x + T1.x, E1.y + T1.y);
  v[2] = make_float2(E2.x + T2.x, E2.y + T2.y);
  v[3] = make_float2(E0.x - O0.x, E0.y - O0.y);
  v[4] = make_float2(E1.x - T1.x, E1.y - T1.y);
  v[5] = make_float2(E2.x - T2.x, E2.y - T2.y);
}

// W24^{sign*j}, j in [0,16) (only a*k6 <= 15 needed). Compile-time folded.
__device__ __forceinline__ float2 w24v(int j, int sign) {
  constexpr float C[16] = {
    1.f, 0.96592582628906831f, 0.86602540378443865f, 0.70710678118654752f,
    0.5f, 0.25881904510252076f, 0.f, -0.25881904510252076f,
    -0.5f, -0.70710678118654752f, -0.86602540378443865f, -0.96592582628906831f,
    -1.f, -0.96592582628906831f, -0.86602540378443865f, -0.70710678118654752f };
  constexpr float S[16] = {
    0.f, 0.25881904510252076f, 0.5f, 0.70710678118654752f,
    0.86602540378443865f, 0.96592582628906831f, 1.f, 0.96592582628906831f,
    0.86602540378443865f, 0.70710678118654752f, 0.5f, 0.25881904510252076f,
    0.f, -0.25881904510252076f, -0.5f, -0.70710678118654752f };
  return make_float2(C[j], sign < 0 ? -S[j] : S[j]);
}

// DFT-24 over registers: 24 = 4(a) x 6(b), x[a+4b].
// Stage1: per a, dft6 over b (in-place into v[a+4*k6]).
// Stage2: per k6, twiddle W24^{a*k6} + dft4 over a -> out[k6+6m].
// Impulse-verified: delta_1 -> W24^{SIGN*k}.
template<int SIGN>
__device__ __forceinline__ void dft24(float2 v[24]) {
#pragma unroll
  for (int a = 0; a < 4; ++a) {
    float2 tmp[6];
#pragma unroll
    for (int b = 0; b < 6; ++b) tmp[b] = v[a + 4 * b];
    dft6<SIGN>(tmp);
#pragma unroll
    for (int k6 = 0; k6 < 6; ++k6) v[a + 4 * k6] = tmp[k6];
  }
  float2 o[24];
#pragma unroll
  for (int k6 = 0; k6 < 6; ++k6) {
    float2 h[4];
    h[0] = v[4 * k6];
#pragma unroll
    for (int a = 1; a < 4; ++a) {
      int j = a * k6;
      h[a] = (j == 0) ? v[a + 4 * k6] : cmulf(v[a + 4 * k6], w24v(j, SIGN));
    }
    dft4<SIGN>(h);
#pragma unroll
    for (int m = 0; m < 4; ++m) o[k6 + 6 * m] = h[m];
  }
#pragma unroll
  for (int i = 0; i < 24; ++i) v[i] = o[i];
}

// ---------------- generic butterfly steps (NR registers) -------------------
template<int H, int NR>
__device__ __forceinline__ void dif_stepN(float2* v, float s, float csl, float snl) {
#pragma unroll
  for (int r = 0; r < NR; ++r) {
    float2 o = exch<H>(v[r]);
    float dx = fmaf(s, v[r].x, o.x);
    float dy = fmaf(s, v[r].y, o.y);
    v[r] = make_float2(dx * csl - dy * snl, dx * snl + dy * csl);
  }
}
template<int H, int NR>
__device__ __forceinline__ void dif_stepN_notw(float2* v, float s) {
#pragma unroll
  for (int r = 0; r < NR; ++r) {
    float2 o = exch<H>(v[r]);
    v[r] = make_float2(fmaf(s, v[r].x, o.x), fmaf(s, v[r].y, o.y));
  }
}
template<int H, int NR>
__device__ __forceinline__ void dit_stepN(float2* v, float s, float csl, float snl) {
#pragma unroll
  for (int r = 0; r < NR; ++r) {
    float2 bt = make_float2(v[r].x * csl - v[r].y * snl,
                            v[r].x * snl + v[r].y * csl);
    float2 o = exch<H>(bt);
    v[r] = make_float2(fmaf(s, bt.x, o.x), fmaf(s, bt.y, o.y));
  }
}
template<int H, int NR>
__device__ __forceinline__ void dit_stepN_notw(float2* v, float s) {
#pragma unroll
  for (int r = 0; r < NR; ++r) {
    float2 o = exch<H>(v[r]);
    v[r] = make_float2(fmaf(s, v[r].x, o.x), fmaf(s, v[r].y, o.y));
  }
}

// dual-register-array wrappers used by p1/p3 (6 regs)
template<int H>
__device__ __forceinline__ void dif_step2(float2 u[6], float2 v[6],
                                          float s, float csl, float snl) {
  dif_stepN<H, 6>(u, s, csl, snl);
  dif_stepN<H, 6>(v, s, csl, snl);
}
template<int H>
__device__ __forceinline__ void dit_step2(float2 u[6], float2 v[6],
                                          float s, float csl, float snl) {
  dit_stepN<H, 6>(u, s, csl, snl);
  dit_stepN<H, 6>(v, s, csl, snl);
}

// ---------------- 64-lane FFT drivers (p1/p3, 6 regs) ----------------------
template<int SIGN>
__device__ __forceinline__ void dif64t(float2 v[6], int t, float tc, float tss) {
  { int j = t & 31; bool hi = (t & 32) != 0;
    float cs = __shfl(tc, j), sn = __shfl(tss, j);
    float s = hi ? -1.f : 1.f, csl = hi ? cs : 1.f, snl = hi ? sn : 0.f;
    dif_stepN<32, 6>(v, s, csl, snl); }
  { int j = (t & 15) << 1; bool hi = (t & 16) != 0;
    float cs = __shfl(tc, j), sn = __shfl(tss, j);
    float s = hi ? -1.f : 1.f, csl = hi ? cs : 1.f, snl = hi ? sn : 0.f;
    dif_stepN<16, 6>(v, s, csl, snl); }
  { int j = (t & 7) << 2; bool hi = (t & 8) != 0;
    float cs = __shfl(tc, j), sn = __shfl(tss, j);
    float s = hi ? -1.f : 1.f, csl = hi ? cs : 1.f, snl = hi ? sn : 0.f;
    dif_stepN<8, 6>(v, s, csl, snl); }
  { int j = (t & 3) << 3; bool hi = (t & 4) != 0;
    float cs = __shfl(tc, j), sn = __shfl(tss, j);
    float s = hi ? -1.f : 1.f, csl = hi ? cs : 1.f, snl = hi ? sn : 0.f;
    dif_stepN<4, 6>(v, s, csl, snl); }
  { bool hi = (t & 2) != 0, iq = (t & 1) != 0;
    float s = hi ? -1.f : 1.f;
    float c2 = (hi && iq) ? 0.f : 1.f;
    float s2 = (hi && iq) ? (float)SIGN : 0.f;
    dif_stepN<2, 6>(v, s, c2, s2); }
  { bool hi = (t & 1) != 0;
    dif_stepN_notw<1, 6>(v, hi ? -1.f : 1.f); }
}

template<int SIGN>
__device__ __forceinline__ void dit64t2(float2 u[6], float2 v[6], int t,
                                        float tc, float tss) {
  { bool hi = (t & 1) != 0;
    float s = hi ? -1.f : 1.f;
    dit_stepN_notw<1, 6>(u, s); dit_stepN_notw<1, 6>(v, s); }
  { bool hi = (t & 2) != 0, iq = (t & 1) != 0;
    float s = hi ? -1.f : 1.f;
    float c2 = (hi && iq) ? 0.f : 1.f;
    float s2 = (hi && iq) ? (float)SIGN : 0.f;
    dit_step2<2>(u, v, s, c2, s2); }
  { int j = (t & 3) << 3; bool hi = (t & 4) != 0;
    float cs = __shfl(tc, j), sn = __shfl(tss, j);
    float s = hi ? -1.f : 1.f, csl = hi ? cs : 1.f, snl = hi ? sn : 0.f;
    dit_step2<4>(u, v, s, csl, snl); }
  { int j = (t & 7) << 2; bool hi = (t & 8) != 0;
    float cs = __shfl(tc, j), sn = __shfl(tss, j);
    float s = hi ? -1.f : 1.f, csl = hi ? cs : 1.f, snl = hi ? sn : 0.f;
    dit_step2<8>(u, v, s, csl, snl); }
  { int j = (t & 15) << 1; bool hi = (t & 16) != 0;
    float cs = __shfl(tc, j), sn = __shfl(tss, j);
    float s = hi ? -1.f : 1.f, csl = hi ? cs : 1.f, snl = hi ? sn : 0.f;
    dit_step2<16>(u, v, s, csl, snl); }
  { int j = t & 31; bool hi = (t & 32) != 0;
    float cs = __shfl(tc, j), sn = __shfl(tss, j);
    float s = hi ? -1.f : 1.f, csl = hi ? cs : 1.f, snl = hi ? sn : 0.f;
    dit_step2<32>(u, v, s, csl, snl); }
}

template<int SIGN>
__device__ __forceinline__ void fwd384t(float2 v[6], int t, float tc, float tss,
                                        const float2 w[5]) {
  dft6<SIGN>(v);
#pragma unroll
  for (int r = 1; r < 6; ++r) v[r] = cmulf(v[r], w[r - 1]);
  dif64t<SIGN>(v, t, tc, tss);
}

template<int SIGN>
__device__ __forceinline__ void bwd384t2(float2 u[6], float2 v[6], int t,
                                         float tc, float tss, const float2 w[5],
                                         float sc0) {
  dit64t2<SIGN>(u, v, t, tc, tss);
  u[0].x *= sc0; u[0].y *= sc0;
  v[0].x *= sc0; v[0].y *= sc0;
#pragma unroll
  for (int r = 1; r < 6; ++r) { u[r] = cmulf(u[r], w[r - 1]); v[r] = cmulf(v[r], w[r - 1]); }
  dft6<SIGN>(u);
  dft6<SIGN>(v);
}

// ---------------- 16-lane FFT drivers (p2, 24 regs) ------------------------
// Stage twiddle exp(SIGN*i*pi*(t&(h-1))/h) = table[j], j=(t&(h-1))*(32/h).
template<int SIGN>
__device__ __forceinline__ void dif16x24(float2 v[24], int t, float tc, float tss) {
  { int j = (t & 7) << 2; bool hi = (t & 8) != 0;   // h=8 (DPP ror)
    float cs = __shfl(tc, j), sn = __shfl(tss, j);
    float s = hi ? -1.f : 1.f, csl = hi ? cs : 1.f, snl = hi ? sn : 0.f;
    dif_stepN<8, 24>(v, s, csl, snl); }
  { int j = (t & 3) << 3; bool hi = (t & 4) != 0;   // h=4 (shfl, LDS pipe)
    float cs = __shfl(tc, j), sn = __shfl(tss, j);
    float s = hi ? -1.f : 1.f, csl = hi ? cs : 1.f, snl = hi ? sn : 0.f;
    dif_stepN<4, 24>(v, s, csl, snl); }
  { bool hi = (t & 2) != 0, iq = (t & 1) != 0;      // h=2 (DPP)
    float s = hi ? -1.f : 1.f;
    float c2 = (hi && iq) ? 0.f : 1.f;
    float s2 = (hi && iq) ? (float)SIGN : 0.f;
    dif_stepN<2, 24>(v, s, c2, s2); }
  { bool hi = (t & 1) != 0;                          // h=1 (DPP, tw=1)
    dif_stepN_notw<1, 24>(v, hi ? -1.f : 1.f); }
}

template<int SIGN>
__device__ __forceinline__ void dit16x24(float2 v[24], int t, float tc, float tss) {
  { bool hi = (t & 1) != 0;
    dit_stepN_notw<1, 24>(v, hi ? -1.f : 1.f); }
  { bool hi = (t & 2) != 0, iq = (t & 1) != 0;
    float s = hi ? -1.f : 1.f;
    float c2 = (hi && iq) ? 0.f : 1.f;
    float s2 = (hi && iq) ? (float)SIGN : 0.f;
    dit_stepN<2, 24>(v, s, c2, s2); }
  { int j = (t & 3) << 3; bool hi = (t & 4) != 0;   // h=4 (shfl)
    float cs = __shfl(tc, j), sn = __shfl(tss, j);
    float s = hi ? -1.f : 1.f, csl = hi ? cs : 1.f, snl = hi ? sn : 0.f;
    dit_stepN<4, 24>(v, s, csl, snl); }
  { int j = (t & 7) << 2; bool hi = (t & 8) != 0;   // h=8 (DPP ror)
    float cs = __shfl(tc, j), sn = __shfl(tss, j);
    float s = hi ? -1.f : 1.f, csl = hi ? cs : 1.f, snl = hi ? sn : 0.f;
    dit_stepN<8, 24>(v, s, csl, snl); }
}

// FWD(24x16): v[r] = col[t16+16r] -> (t16,k1) holds X[k1 + 24*brev4(t16)].
// Twiddle W384^{SIGN*t*k1} = P[k1/6]*Q[k1%6] (powers of w0=e^{SIGN*2pi i t/384}).
template<int SIGN>
__device__ __forceinline__ void fwd384q(float2 v[24], int t16, float tc, float tss,
                                        const float2 Q[6], const float2 P[4]) {
  dft24<SIGN>(v);
#pragma unroll
  for (int k1 = 1; k1 < 24; ++k1) {
    int m = k1 / 6, q = k1 % 6;
    float2 x = v[k1];
    if (q) x = cmulf(x, Q[q]);
    if (m) x = cmulf(x, P[m]);
    v[k1] = x;
  }
  dif16x24<SIGN>(v, t16, tc, tss);
}

// BWD(24x16): exact inverse; P[m>=1] carry the 1/N scale, m==0 scales by inv.
template<int SIGN>
__device__ __forceinline__ void bwd384q(float2 v[24], int t16, float tc, float tss,
                                        const float2 Q[6], const float2 P[4],
                                        float inv) {
  dit16x24<SIGN>(v, t16, tc, tss);
#pragma unroll
  for (int k1 = 0; k1 < 24; ++k1) {
    int m = k1 / 6, q = k1 % 6;
    float2 x = v[k1];
    if (q) x = cmulf(x, Q[q]);
    if (m) x = cmulf(x, P[m]);
    else   x = make_float2(x.x * inv, x.y * inv);
    v[k1] = x;
  }
  dft24<SIGN>(v);
}

// ---------------- old LDS fft384 (precompute kernels only) -----------------
template<int R, int NS, int DIR>
__device__ __forceinline__ void fft_stage(const float2* S, float2* D, int t) {
  constexpr int NR = NN / R;
#pragma unroll
  for (int rep = 0; rep < (NR + 63) / 64; ++rep) {
    int j = t + rep * 64;
    if (j < NR) {
      float2 v[R];
#pragma unroll
      for (int r = 0; r < R; ++r) v[r] = S[LID(j + r * NR)];
      if constexpr (NS > 1) {
        float ang = (float)DIR * (TWOPI_F / (float)(NS * R)) * (float)(j % NS);
        float sv, cv;
        __sincosf(ang, &sv, &cv);
        float2 w = make_float2(cv, sv);
        float2 wr = w;
#pragma unroll
        for (int r = 1; r < R; ++r) { v[r] = cmulf(v[r], wr); wr = cmulf(wr, w); }
      }
      if constexpr (R == 4) dft4<DIR>(v); else dft6<DIR>(v);
      int base = (j / NS) * (NS * R) + (j % NS);
#pragma unroll
      for (int r = 0; r < R; ++r) D[LID(base + r * NS)] = v[r];
    }
  }
}

template<int DIR>
__device__ __forceinline__ void fft384(float2* A, float2* Bf, int t) {
  fft_stage<4, 1,  DIR>(A,  Bf, t); __syncthreads();
  fft_stage<4, 4,  DIR>(Bf, A,  t); __syncthreads();
  fft_stage<4, 16, DIR>(A,  Bf, t); __syncthreads();
  fft_stage<6, 64, DIR>(Bf, A,  t); __syncthreads();
}

// ---------------- E: iteration 1 (y0 = 0 -> xn = cz), elementwise ----------
__global__ __launch_bounds__(256) void k_e(const float2* __restrict__ czb,
                                           float2* __restrict__ xbuf,
                                           float2* __restrict__ ybuf) {
  long i = (long)blockIdx.x * 256 + threadIdx.x;
  float2 cz = czb[i];
  float2 x = make_float2(fmaxf(cz.x, 0.f), fmaxf(cz.y, 0.f));
  xbuf[i] = x;
  ybuf[i] = x;   // t1 = 1 -> y1 = x1
}

// ---------------- P1: row FFT of coil*y -> W1 (permuted-x storage) ---------
// grid B*C*384/4, 256 thr; one wave per row; no LDS, no barriers.
__global__ __launch_bounds__(256) void k_p1(const float2* __restrict__ ybuf,
                                            const float* __restrict__ csm,
                                            float2* __restrict__ W1) {
  int t = threadIdx.x & 63;
  int w = threadIdx.x >> 6;
  long gl = (long)blockIdx.x * 4 + w;       // (b*C + c)*384 + y
  int y = (int)(gl % NN);
  long bc = gl / NN;
  long b = bc >> 4, c = bc & 15;
  long rowoff = (long)y * NN;
  float tc, ts; __sincosf((float)(t & 31) * (PI_F / 32.0f), &ts, &tc);
  float tsf = -ts;                           // fwd (SIGN=-1) pre-signed
  float2 w0; __sincosf(-(float)t * (TWOPI_F / 384.0f), &w0.y, &w0.x);
  float2 wf[5];
  wf[0] = w0;
#pragma unroll
  for (int r = 1; r < 5; ++r) wf[r] = cmulf(wf[r - 1], w0);
  const float2* yrow = ybuf + b * (long)(NN * NN) + rowoff;
  const float* crow_re = csm + (b * 2 * CC + c) * (long)(NN * NN) + rowoff;
  const float* crow_im = crow_re + (long)CC * NN * NN;
  float2 v[6];
#pragma unroll
  for (int k = 0; k < 6; ++k) {
    int x = t + 64 * k;
    float2 yv = yrow[x];
    float cre = crow_re[x], cim = crow_im[x];
    v[k] = make_float2(yv.x * cre - yv.y * cim, yv.x * cim + yv.y * cre);
  }
  fwd384t<-1>(v, t, tc, tsf, wf);
  float2* orow = W1 + gl * NN;
#pragma unroll
  for (int r = 0; r < 6; ++r) orow[t + 64 * r] = v[r];
}

// ---------------- P2: col FFT -> mask -> col IFFT, in-place on W1 ----------
// grid B*C*(N/8)=3072 blocks, 128 thr. 8-col planar tile, pad 392.
// Each 16-lane group (= one DPP row) owns one column, 24 regs deep.
// XCD-chunked swizzle. 1/N folded into bwd twiddles.
#define P2PAD 392
__global__ __launch_bounds__(128) void k_p2(float2* __restrict__ W1,
                                            const unsigned char* __restrict__ maskPT) {
  __shared__ float ldsR[8][P2PAD];
  __shared__ float ldsI[8][P2PAD];
  int tid = threadIdx.x;
  const int nwg = BB * CC * (NN / 8);            // 3072, divisible by 8
  int l = ((int)blockIdx.x & 7) * (nwg >> 3) + ((int)blockIdx.x >> 3);
  int xt = l % (NN / 8);
  long bc = l / (NN / 8);
  long b = bc >> 4;
  int s0 = xt * 8;
  long sbase = bc * (long)(NN * NN);
  int g = tid >> 4, t16 = tid & 15;
  int tl = tid & 63;
  // twiddle table (lane j of wave holds cos/sin(pi*j/32))
  float tc, ts; __sincosf((float)(tl & 31) * (PI_F / 32.0f), &ts, &tc);
  float tsf = -ts;
  // W384^{t16*k1} power ladders (fwd sign -, bwd sign +)
  float2 w0; __sincosf(-(float)t16 * (TWOPI_F / 384.0f), &w0.y, &w0.x);
  float2 q2 = cmulf(w0, w0);
  float2 q3 = cmulf(q2, w0);
  float2 q4 = cmulf(q2, q2);
  float2 q5 = cmulf(q3, q2);
  float2 p1v = cmulf(q3, q3);     // w^6
  float2 p2v = cmulf(p1v, p1v);   // w^12
  float2 p3v = cmulf(p2v, p1v);   // w^18
  float2 Qf[6] = { make_float2(1.f, 0.f), w0, q2, q3, q4, q5 };
  float2 Pf[4] = { make_float2(1.f, 0.f), p1v, p2v, p3v };
  const float inv = 1.0f / NN;
  float2 Qb[6], Pb[4];
  Qb[0] = make_float2(1.f, 0.f);
#pragma unroll
  for (int i = 1; i < 6; ++i) Qb[i] = make_float2(Qf[i].x, -Qf[i].y);
  Pb[0] = make_float2(inv, 0.f);  // unused (m==0 path scales by inv)
#pragma unroll
  for (int m = 1; m < 4; ++m) Pb[m] = make_float2(Pf[m].x * inv, -Pf[m].y * inv);
  // fill: float4 (2 complex) per op; 12 ops/thread (128 thr)
  const float4* W1v = (const float4*)W1;
  long f4base = (sbase >> 1) + (s0 >> 1);
#pragma unroll
  for (int k = 0; k < 12; ++k) {
    int e = tid + k * 128; int y = e >> 2; int q = e & 3;
    float4 val = W1v[f4base + (long)y * (NN / 2) + q];
    ldsR[2 * q][y] = val.x; ldsI[2 * q][y] = val.y;
    ldsR[2 * q + 1][y] = val.z; ldsI[2 * q + 1][y] = val.w;
  }
  __syncthreads();
  {
    float2 v[24];
#pragma unroll
    for (int r = 0; r < 24; ++r)
      v[r] = make_float2(ldsR[g][t16 + 16 * r], ldsI[g][t16 + 16 * r]);
    fwd384q<-1>(v, t16, tc, tsf, Qf, Pf);
    // mask: freq at (t16,k1) = k1 + 24*brev4(t16); 6 x uchar4 loads
    int brt = (int)(__brev((unsigned)t16) >> 28);
    const unsigned char* mcol =
        maskPT + b * (long)(NN * NN) + (long)(s0 + g) * NN + 24 * brt;
#pragma unroll
    for (int i = 0; i < 6; ++i) {
      uchar4 mv = ((const uchar4*)mcol)[i];
      v[4 * i + 0].x *= (float)mv.x; v[4 * i + 0].y *= (float)mv.x;
      v[4 * i + 1].x *= (float)mv.y; v[4 * i + 1].y *= (float)mv.y;
      v[4 * i + 2].x *= (float)mv.z; v[4 * i + 2].y *= (float)mv.z;
      v[4 * i + 3].x *= (float)mv.w; v[4 * i + 3].y *= (float)mv.w;
    }
    bwd384q<1>(v, t16, tc, ts, Qb, Pb, inv);
#pragma unroll
    for (int r = 0; r < 24; ++r) {
      ldsR[g][t16 + 16 * r] = v[r].x;
      ldsI[g][t16 + 16 * r] = v[r].y;
    }
  }
  __syncthreads();
  float4* W1o = (float4*)W1;
#pragma unroll
  for (int k = 0; k < 12; ++k) {
    int e = tid + k * 128; int y = e >> 2; int q = e & 3;
    float4 val;
    val.x = ldsR[2 * q][y]; val.y = ldsI[2 * q][y];
    val.z = ldsR[2 * q + 1][y]; val.w = ldsI[2 * q + 1][y];
    W1o[f4base + (long)y * (NN / 2) + q] = val;
  }
}

// ---------------- P3: row IFFT + conj(coil) reduce + FISTA update ----------
// grid B*384 blocks, 256 thr; wave w handles coils 4w..4w+3 (2 at a time);
// LDS reduce. Update: x = prox((1-lam)(y - Q) + cz).
// last!=0: write planar output instead of x/y (final iteration).
__global__ __launch_bounds__(256) void k_p3(const float2* __restrict__ W1,
                                            const float* __restrict__ csm,
                                            const float2* __restrict__ czb,
                                            const float* __restrict__ lamp,
                                            float2* __restrict__ xbuf,
                                            float2* __restrict__ ybuf,
                                            float* __restrict__ outp,
                                            float beta, int last) {
  __shared__ float2 part[4][NN];
  int tid = threadIdx.x;
  int w = tid >> 6, t = tid & 63;
  long gl = blockIdx.x;            // b*384 + y
  long b = gl / NN;
  int y = (int)(gl % NN);
  long rowoff = (long)y * NN;
  float tc, ts; __sincosf((float)(t & 31) * (PI_F / 32.0f), &ts, &tc);
  float2 w0; __sincosf((float)t * (TWOPI_F / 384.0f), &w0.y, &w0.x);
  float2 wb[5];
  wb[0] = w0;
#pragma unroll
  for (int r = 1; r < 5; ++r) wb[r] = cmulf(wb[r - 1], w0);
  float2 acc[6];
#pragma unroll
  for (int k = 0; k < 6; ++k) acc[k] = make_float2(0.f, 0.f);
#pragma unroll
  for (int ci = 0; ci < 4; ci += 2) {
    int c0 = w * 4 + ci, c1 = c0 + 1;
    const float2* row0 = W1 + ((b * CC + c0) * (long)NN + y) * NN;
    const float2* row1 = W1 + ((b * CC + c1) * (long)NN + y) * NN;
    float2 u[6], v[6];
#pragma unroll
    for (int r = 0; r < 6; ++r) { u[r] = row0[t + 64 * r]; v[r] = row1[t + 64 * r]; }
    bwd384t2<1>(u, v, t, tc, ts, wb, 1.0f);
    const float* cre0 = csm + (b * 2 * CC + c0) * (long)(NN * NN) + rowoff;
    const float* cim0 = cre0 + (long)CC * NN * NN;
    const float* cre1 = csm + (b * 2 * CC + c1) * (long)(NN * NN) + rowoff;
    const float* cim1 = cre1 + (long)CC * NN * NN;
#pragma unroll
    for (int k = 0; k < 6; ++k) {
      int x = t + 64 * k;
      float a0 = cre0[x], b0 = cim0[x];
      float a1 = cre1[x], b1 = cim1[x];
      acc[k].x += (a0 * u[k].x + b0 * u[k].y) + (a1 * v[k].x + b1 * v[k].y);
      acc[k].y += (a0 * u[k].y - b0 * u[k].x) + (a1 * v[k].y - b1 * v[k].x);
    }
  }
#pragma unroll
  for (int k = 0; k < 6; ++k) part[w][t + 64 * k] = acc[k];
  __syncthreads();
  float lamv = lamp[0];
  float oml = 1.0f - lamv;
  long pbase = b * (long)(NN * NN) + rowoff;
  for (int e = tid; e < NN; e += 256) {
    float Qx = (part[0][e].x + part[1][e].x + part[2][e].x + part[3][e].x) * (1.0f / NN);
    float Qy = (part[0][e].y + part[1][e].y + part[2][e].y + part[3][e].y) * (1.0f / NN);
    float2 yv = ybuf[pbase + e];
    float2 cz = czb[pbase + e];
    float xr = oml * (yv.x - Qx) + cz.x;
    float xi = oml * (yv.y - Qy) + cz.y;
    xr = fmaxf(xr, 0.f);
    xi = fmaxf(xi, 0.f);
    if (last) {
      outp[(b * 2 + 0) * (long)(NN * NN) + rowoff + e] = xr;
      outp[(b * 2 + 1) * (long)(NN * NN) + rowoff + e] = xi;
    } else {
      float2 xo = xbuf[pbase + e];
      xbuf[pbase + e] = make_float2(xr, xi);
      ybuf[pbase + e] = make_float2(xr + beta * (xr - xo.x), xi + beta * (xi - xo.y));
    }
  }
}

// ---------------- mask permutation precompute (one-time) -------------------
// maskPT[b][sx][y] = mask[b][y][P64(sx)], P64(s) = (s>>6) + 6*brev6(s&63).
// (y stays natural: p2 computes its own y-frequency index in-kernel.)
__global__ __launch_bounds__(256) void k_mpre(const int* __restrict__ mask,
                                              unsigned char* __restrict__ maskPT) {
  long i = (long)blockIdx.x * 256 + threadIdx.x;
  long b = i / (NN * NN);
  int rem = (int)(i % (NN * NN));
  int sx = rem / NN, y = rem % NN;
  int fx = (sx >> 6) + 6 * (int)(__brev((unsigned)(sx & 63)) >> 26);
  maskPT[i] = (unsigned char)mask[b * (long)(NN * NN) + (long)y * NN + fx];
}

// ---------------- precompute: cz = (1-lam)*cst + lam*z ---------------------
__global__ __launch_bounds__(256) void k_preA(const float* __restrict__ x0,
                                              const int* __restrict__ mask,
                                              float2* __restrict__ T) {
  __shared__ float2 U[4][LNPAD], V[4][LNPAD];
  int tid = threadIdx.x;
  int line = tid >> 6, t = tid & 63;
  long gl0 = (long)blockIdx.x * 4;
#pragma unroll
  for (int k = 0; k < 6; ++k) {
    int e = tid + k * 256; int l = e / NN; int x = e % NN;
    long gl = gl0 + l;
    long b = gl / NN;
    int y = (int)(gl % NN);
    long pidx = (long)y * NN + x;
    float mv = (float)mask[b * (long)(NN * NN) + pidx];
    float br = x0[(b * 2 + 0) * (long)(NN * NN) + pidx] * mv;
    float bi = x0[(b * 2 + 1) * (long)(NN * NN) + pidx] * mv;
    U[l][LID(x)] = make_float2(br, bi);
  }
  __syncthreads();
  fft384<1>(U[line], V[line], t);
#pragma unroll
  for (int k = 0; k < 6; ++k) {
    int e = tid + k * 256; int l = e / NN; int x = e % NN;
    float2 u = U[l][LID(x)];
    T[(gl0 + l) * NN + x] = make_float2(u.x * (1.0f / NN), u.y * (1.0f / NN));
  }
}

__global__ __launch_bounds__(256) void k_preB(const float2* __restrict__ T,
                                              float2* __restrict__ r0) {
  __shared__ float2 tile[NN][17];
  __shared__ float2 U[4][LNPAD], V[4][LNPAD];
  int tid = threadIdx.x;
  int xt = blockIdx.x % (NN / 16);
  long b = blockIdx.x / (NN / 16);
  int x0c = xt * 16;
  long sbase = b * (long)(NN * NN);
#pragma unroll
  for (int k = 0; k < 24; ++k) {
    int e = tid + k * 256; int y = e >> 4; int c = e & 15;
    tile[y][c] = T[sbase + (long)y * NN + x0c + c];
  }
  __syncthreads();
  int line = tid >> 6, t = tid & 63;
  for (int g = 0; g < 4; ++g) {
#pragma unroll
    for (int k = 0; k < 6; ++k) {
      int e = tid + k * 256; int l = e / NN; int y = e % NN;
      U[l][LID(y)] = tile[y][4 * g + l];
    }
    __syncthreads();
    fft384<1>(U[line], V[line], t);
#pragma unroll
    for (int k = 0; k < 6; ++k) {
      int e = tid + k * 256; int l = e / NN; int y = e % NN;
      float2 u = U[l][LID(y)];
      tile[y][4 * g + l] = make_float2(u.x * (1.0f / NN), u.y * (1.0f / NN));
    }
    __syncthreads();
  }
#pragma unroll
  for (int k = 0; k < 24; ++k) {
    int e = tid + k * 256; int y = e >> 4; int c = e & 15;
    r0[sbase + (long)y * NN + x0c + c] = tile[y][c];
  }
}

__global__ __launch_bounds__(256) void k_preC(const float* __restrict__ csm,
                                              const float2* __restrict__ r0,
                                              const float* __restrict__ zk,
                                              const float* __restrict__ lamp,
                                              float2* __restrict__ czb) {
  long i = (long)blockIdx.x * 256 + threadIdx.x;
  long b = i / (NN * NN);
  long p = i % (NN * NN);
  float sr = 0.f, si = 0.f;
#pragma unroll
  for (int c = 0; c < CC; ++c) {
    sr += csm[(b * 2 * CC + c) * (long)(NN * NN) + p];
    si -= csm[((b * 2 + 1) * CC + c) * (long)(NN * NN) + p];
  }
  float2 r = r0[i];
  float cstx = sr * r.x - si * r.y;
  float csty = sr * r.y + si * r.x;
  float lamv = lamp[0];
  float oml = 1.0f - lamv;
  float zr = zk[(b * 2 + 0) * (long)(NN * NN) + p];
  float zi = zk[(b * 2 + 1) * (long)(NN * NN) + p];
  czb[i] = make_float2(oml * cstx + lamv * zr, oml * csty + lamv * zi);
}

extern "C" void kernel_launch(void* const* d_in, const int* in_sizes, int n_in,
                              void* d_out, int out_size, void* d_ws, size_t ws_size,
                              hipStream_t stream) {
  const float* zk  = (const float*)d_in[0];
  const float* x0  = (const float*)d_in[1];
  const float* csm = (const float*)d_in[2];
  const float* lam = (const float*)d_in[3];
  const int*   msk = (const int*)d_in[4];
  float* out = (float*)d_out;

  // ws layout (float2 units): W1 [B*C*N*N] | y | x | cz | maskPT(uchar)
  size_t img = (size_t)BB * NN * NN;
  float2* W1   = (float2*)d_ws;
  float2* ybuf = W1 + (size_t)BB * CC * NN * NN;
  float2* xbuf = ybuf + img;
  float2* czb  = xbuf + img;
  unsigned char* maskPT = (unsigned char*)(czb + img);
  float2* T  = W1;        // precompute scratch overlays W1
  float2* r0 = W1 + img;

  double tcur = 1.0;
  float betas[NITER];
  for (int i = 0; i < NITER; ++i) {
    double tn = (1.0 + sqrt(1.0 + 4.0 * tcur * tcur)) * 0.5;
    betas[i] = (float)((tcur - 1.0) / tn);
    tcur = tn;
  }

  k_mpre<<<(BB * NN * NN) / 256, 256, 0, stream>>>(msk, maskPT);
  k_preA<<<BB * NN / 4, 256, 0, stream>>>(x0, msk, T);
  k_preB<<<BB * (NN / 16), 256, 0, stream>>>(T, r0);
  k_preC<<<(BB * NN * NN) / 256, 256, 0, stream>>>(csm, r0, zk, lam, czb);
  // iteration 1 (y0 = 0): x1 = prox(cz)
  k_e<<<(BB * NN * NN) / 256, 256, 0, stream>>>(czb, xbuf, ybuf);
  // iterations 2..20: forward, mask round-trip, adjoint+update
  for (int i = 1; i < NITER; ++i) {
    k_p1<<<BB * CC * NN / 4, 256, 0, stream>>>(ybuf, csm, W1);
    k_p2<<<BB * CC * (NN / 8), 128, 0, stream>>>(W1, maskPT);
    k_p3<<<BB * NN, 256, 0, stream>>>(W1, csm, czb, lam, xbuf, ybuf, out,
                                      betas[i], (i == NITER - 1) ? 1 : 0);
  }
}

// Round 18
// 1836.282 us; speedup vs baseline: 1.2278x; 1.0267x over previous
//
#include <hip/hip_runtime.h>
#include <math.h>

// FISTA data-consistency with masked multi-coil 2D FFT operator.
// B=4, C=16, H=W=384.
// p1/p3: register FFT 384 = 6 regs x 64 lanes (R16 form, verified).
// p2: 384 = 24 regs x 16 lanes — lane-FFT-16 stages h=8(DPP ror),
// h=4(shfl, the ONLY LDS-pipe stage), h=2,1(DPP quad). R18: 256-thr blocks,
// 16-col tile (16 DPP-row groups), PAD=394 (2PAD=20 mod 32: fill 2-way free,
// reads <=3-way) — R17's 128-thr blocks measured 21.7% occupancy; per-lane
// math identical so absmax must stay bit-exact.
// DFT-24 per lane = 4x dft6 + W24-constant twiddles + 6x dft4.
// Mask: y-freq at (t16,k1) = k1 + 24*brev4(t16) computed in-kernel;
// maskPT permutes x only.
// R3: don't fuse p3+p1. R8: fp16 W1 FAILS (range). R9: builtins only.
// R11: short live ranges. R14: permlane builtin ~5 VALU ops (avoid).
// R15: don't widen per-wave ILP past 2 cols at 6-reg (conflicts+occupancy).

#define NN 384
#define BB 4
#define CC 16
#define NITER 20
#define LNPAD 432   // old LDS path (precompute only)
#define PI_F 3.14159265358979323846f
#define TWOPI_F 6.28318530717958647692f

__device__ __forceinline__ int LID(int i) { return i + (i >> 3); }

__device__ __forceinline__ float2 cmulf(float2 a, float2 b) {
  return make_float2(a.x * b.x - a.y * b.y, a.x * b.y + a.y * b.x);
}

// ---------------- cross-lane exchange primitives ---------------------------
// DPP: quad_perm 0xB1 (xor-1), 0x4E (xor-2), row_ror:8 = 0x128 (xor-8 within
// 16-lane rows; (i+-8)%16 == i^8). All HW-verified bit-exact (R12/R16).
template<int CTRL>
__device__ __forceinline__ float dppx(float v) {
  int s = __float_as_int(v);
  return __int_as_float(__builtin_amdgcn_update_dpp(s, s, CTRL, 0xF, 0xF, true));
}

template<int H>
__device__ __forceinline__ float2 exch(float2 v) {
  if constexpr (H == 1) {
    return make_float2(dppx<0xB1>(v.x), dppx<0xB1>(v.y));   // quad [1,0,3,2]
  } else if constexpr (H == 2) {
    return make_float2(dppx<0x4E>(v.x), dppx<0x4E>(v.y));   // quad [2,3,0,1]
  } else if constexpr (H == 8) {
    return make_float2(dppx<0x128>(v.x), dppx<0x128>(v.y)); // row_ror:8
  } else {
    return make_float2(__shfl_xor(v.x, H), __shfl_xor(v.y, H));
  }
}

template<int DIR>
__device__ __forceinline__ void dft4(float2* v) {
  float ax = v[0].x + v[2].x, ay = v[0].y + v[2].y;
  float bx = v[0].x - v[2].x, by = v[0].y - v[2].y;
  float cx = v[1].x + v[3].x, cy = v[1].y + v[3].y;
  float dx = v[1].x - v[3].x, dy = v[1].y - v[3].y;
  float dix, diy;
  if (DIR < 0) { dix = dy; diy = -dx; }
  else         { dix = -dy; diy = dx; }
  v[0] = make_float2(ax + cx, ay + cy);
  v[2] = make_float2(ax - cx, ay - cy);
  v[1] = make_float2(bx + dix, by + diy);
  v[3] = make_float2(bx - dix, by - diy);
}

// DFT-3: X1 = m + i*s*S3*d, X2 = m - i*s*S3*d; m = a - u/2, u=b+c, d=b-c.
template<int SIGN>
__device__ __forceinline__ void dft3(float2 a, float2 b, float2 c,
                                     float2& X0, float2& X1, float2& X2) {
  const float S3 = 0.86602540378443864676f;
  float ux = b.x + c.x, uy = b.y + c.y;
  float dx = b.x - c.x, dy = b.y - c.y;
  float mx = a.x - 0.5f * ux, my = a.y - 0.5f * uy;
  float ex = S3 * dx, ey = S3 * dy;
  X0 = make_float2(a.x + ux, a.y + uy);
  if (SIGN < 0) {
    X1 = make_float2(mx + ey, my - ex);
    X2 = make_float2(mx - ey, my + ex);
  } else {
    X1 = make_float2(mx - ey, my + ex);
    X2 = make_float2(mx + ey, my - ex);
  }
}

// Fast DFT-6 = two DFT-3 + trivial W6 twiddles. Verified on impulses.
template<int SIGN>
__device__ __forceinline__ void dft6(float2* v) {
  const float S3 = 0.86602540378443864676f;
  float2 E0, E1, E2, O0, O1, O2;
  dft3<SIGN>(v[0], v[2], v[4], E0, E1, E2);
  dft3<SIGN>(v[1], v[3], v[5], O0, O1, O2);
  const float ss = (SIGN < 0) ? -S3 : S3;
  float2 T1 = cmulf(O1, make_float2(0.5f, ss));
  float2 T2 = cmulf(O2, make_float2(-0.5f, ss));
  v[0] = make_float2(E0.x + O0.x, E0.y + O0.y);
  v[1] = make_float2(E1.x + T1.x, E1.y + T1.y);
  v[2] = make_float2(E2.x + T2.x, E2.y + T2.y);
  v[3] = make_float2(E0.x - O0.x, E0.y - O0.y);
  v[4] = make_float2(E1.x - T1.x, E1.y - T1.y);
  v[5] = make_float2(E2.x - T2.x, E2.y - T2.y);
}

// W24^{sign*j}, j in [0,16). Compile-time folded.
__device__ __forceinline__ float2 w24v(int j, int sign) {
  constexpr float C[16] = {
    1.f, 0.96592582628906831f, 0.86602540378443865f, 0.70710678118654752f,
    0.5f, 0.25881904510252076f, 0.f, -0.25881904510252076f,
    -0.5f, -0.70710678118654752f, -0.86602540378443865f, -0.96592582628906831f,
    -1.f, -0.96592582628906831f, -0.86602540378443865f, -0.70710678118654752f };
  constexpr float S[16] = {
    0.f, 0.25881904510252076f, 0.5f, 0.70710678118654752f,
    0.86602540378443865f, 0.96592582628906831f, 1.f, 0.96592582628906831f,
    0.86602540378443865f, 0.70710678118654752f, 0.5f, 0.25881904510252076f,
    0.f, -0.25881904510252076f, -0.5f, -0.70710678118654752f };
  return make_float2(C[j], sign < 0 ? -S[j] : S[j]);
}

// DFT-24 over registers: 24 = 4(a) x 6(b), x[a+4b]. Impulse-verified.
template<int SIGN>
__device__ __forceinline__ void dft24(float2 v[24]) {
#pragma unroll
  for (int a = 0; a < 4; ++a) {
    float2 tmp[6];
#pragma unroll
    for (int b = 0; b < 6; ++b) tmp[b] = v[a + 4 * b];
    dft6<SIGN>(tmp);
#pragma unroll
    for (int k6 = 0; k6 < 6; ++k6) v[a + 4 * k6] = tmp[k6];
  }
  float2 o[24];
#pragma unroll
  for (int k6 = 0; k6 < 6; ++k6) {
    float2 h[4];
    h[0] = v[4 * k6];
#pragma unroll
    for (int a = 1; a < 4; ++a) {
      int j = a * k6;
      h[a] = (j == 0) ? v[a + 4 * k6] : cmulf(v[a + 4 * k6], w24v(j, SIGN));
    }
    dft4<SIGN>(h);
#pragma unroll
    for (int m = 0; m < 4; ++m) o[k6 + 6 * m] = h[m];
  }
#pragma unroll
  for (int i = 0; i < 24; ++i) v[i] = o[i];
}

// ---------------- generic butterfly steps (NR registers) -------------------
template<int H, int NR>
__device__ __forceinline__ void dif_stepN(float2* v, float s, float csl, float snl) {
#pragma unroll
  for (int r = 0; r < NR; ++r) {
    float2 o = exch<H>(v[r]);
    float dx = fmaf(s, v[r].x, o.x);
    float dy = fmaf(s, v[r].y, o.y);
    v[r] = make_float2(dx * csl - dy * snl, dx * snl + dy * csl);
  }
}
template<int H, int NR>
__device__ __forceinline__ void dif_stepN_notw(float2* v, float s) {
#pragma unroll
  for (int r = 0; r < NR; ++r) {
    float2 o = exch<H>(v[r]);
    v[r] = make_float2(fmaf(s, v[r].x, o.x), fmaf(s, v[r].y, o.y));
  }
}
template<int H, int NR>
__device__ __forceinline__ void dit_stepN(float2* v, float s, float csl, float snl) {
#pragma unroll
  for (int r = 0; r < NR; ++r) {
    float2 bt = make_float2(v[r].x * csl - v[r].y * snl,
                            v[r].x * snl + v[r].y * csl);
    float2 o = exch<H>(bt);
    v[r] = make_float2(fmaf(s, bt.x, o.x), fmaf(s, bt.y, o.y));
  }
}
template<int H, int NR>
__device__ __forceinline__ void dit_stepN_notw(float2* v, float s) {
#pragma unroll
  for (int r = 0; r < NR; ++r) {
    float2 o = exch<H>(v[r]);
    v[r] = make_float2(fmaf(s, v[r].x, o.x), fmaf(s, v[r].y, o.y));
  }
}

// dual-register-array wrappers used by p1/p3 (6 regs)
template<int H>
__device__ __forceinline__ void dif_step2(float2 u[6], float2 v[6],
                                          float s, float csl, float snl) {
  dif_stepN<H, 6>(u, s, csl, snl);
  dif_stepN<H, 6>(v, s, csl, snl);
}
template<int H>
__device__ __forceinline__ void dit_step2(float2 u[6], float2 v[6],
                                          float s, float csl, float snl) {
  dit_stepN<H, 6>(u, s, csl, snl);
  dit_stepN<H, 6>(v, s, csl, snl);
}

// ---------------- 64-lane FFT drivers (p1/p3, 6 regs) ----------------------
template<int SIGN>
__device__ __forceinline__ void dif64t(float2 v[6], int t, float tc, float tss) {
  { int j = t & 31; bool hi = (t & 32) != 0;
    float cs = __shfl(tc, j), sn = __shfl(tss, j);
    float s = hi ? -1.f : 1.f, csl = hi ? cs : 1.f, snl = hi ? sn : 0.f;
    dif_stepN<32, 6>(v, s, csl, snl); }
  { int j = (t & 15) << 1; bool hi = (t & 16) != 0;
    float cs = __shfl(tc, j), sn = __shfl(tss, j);
    float s = hi ? -1.f : 1.f, csl = hi ? cs : 1.f, snl = hi ? sn : 0.f;
    dif_stepN<16, 6>(v, s, csl, snl); }
  { int j = (t & 7) << 2; bool hi = (t & 8) != 0;
    float cs = __shfl(tc, j), sn = __shfl(tss, j);
    float s = hi ? -1.f : 1.f, csl = hi ? cs : 1.f, snl = hi ? sn : 0.f;
    dif_stepN<8, 6>(v, s, csl, snl); }
  { int j = (t & 3) << 3; bool hi = (t & 4) != 0;
    float cs = __shfl(tc, j), sn = __shfl(tss, j);
    float s = hi ? -1.f : 1.f, csl = hi ? cs : 1.f, snl = hi ? sn : 0.f;
    dif_stepN<4, 6>(v, s, csl, snl); }
  { bool hi = (t & 2) != 0, iq = (t & 1) != 0;
    float s = hi ? -1.f : 1.f;
    float c2 = (hi && iq) ? 0.f : 1.f;
    float s2 = (hi && iq) ? (float)SIGN : 0.f;
    dif_stepN<2, 6>(v, s, c2, s2); }
  { bool hi = (t & 1) != 0;
    dif_stepN_notw<1, 6>(v, hi ? -1.f : 1.f); }
}

template<int SIGN>
__device__ __forceinline__ void dit64t2(float2 u[6], float2 v[6], int t,
                                        float tc, float tss) {
  { bool hi = (t & 1) != 0;
    float s = hi ? -1.f : 1.f;
    dit_stepN_notw<1, 6>(u, s); dit_stepN_notw<1, 6>(v, s); }
  { bool hi = (t & 2) != 0, iq = (t & 1) != 0;
    float s = hi ? -1.f : 1.f;
    float c2 = (hi && iq) ? 0.f : 1.f;
    float s2 = (hi && iq) ? (float)SIGN : 0.f;
    dit_step2<2>(u, v, s, c2, s2); }
  { int j = (t & 3) << 3; bool hi = (t & 4) != 0;
    float cs = __shfl(tc, j), sn = __shfl(tss, j);
    float s = hi ? -1.f : 1.f, csl = hi ? cs : 1.f, snl = hi ? sn : 0.f;
    dit_step2<4>(u, v, s, csl, snl); }
  { int j = (t & 7) << 2; bool hi = (t & 8) != 0;
    float cs = __shfl(tc, j), sn = __shfl(tss, j);
    float s = hi ? -1.f : 1.f, csl = hi ? cs : 1.f, snl = hi ? sn : 0.f;
    dit_step2<8>(u, v, s, csl, snl); }
  { int j = (t & 15) << 1; bool hi = (t & 16) != 0;
    float cs = __shfl(tc, j), sn = __shfl(tss, j);
    float s = hi ? -1.f : 1.f, csl = hi ? cs : 1.f, snl = hi ? sn : 0.f;
    dit_step2<16>(u, v, s, csl, snl); }
  { int j = t & 31; bool hi = (t & 32) != 0;
    float cs = __shfl(tc, j), sn = __shfl(tss, j);
    float s = hi ? -1.f : 1.f, csl = hi ? cs : 1.f, snl = hi ? sn : 0.f;
    dit_step2<32>(u, v, s, csl, snl); }
}

template<int SIGN>
__device__ __forceinline__ void fwd384t(float2 v[6], int t, float tc, float tss,
                                        const float2 w[5]) {
  dft6<SIGN>(v);
#pragma unroll
  for (int r = 1; r < 6; ++r) v[r] = cmulf(v[r], w[r - 1]);
  dif64t<SIGN>(v, t, tc, tss);
}

template<int SIGN>
__device__ __forceinline__ void bwd384t2(float2 u[6], float2 v[6], int t,
                                         float tc, float tss, const float2 w[5],
                                         float sc0) {
  dit64t2<SIGN>(u, v, t, tc, tss);
  u[0].x *= sc0; u[0].y *= sc0;
  v[0].x *= sc0; v[0].y *= sc0;
#pragma unroll
  for (int r = 1; r < 6; ++r) { u[r] = cmulf(u[r], w[r - 1]); v[r] = cmulf(v[r], w[r - 1]); }
  dft6<SIGN>(u);
  dft6<SIGN>(v);
}

// ---------------- 16-lane FFT drivers (p2, 24 regs) ------------------------
template<int SIGN>
__device__ __forceinline__ void dif16x24(float2 v[24], int t, float tc, float tss) {
  { int j = (t & 7) << 2; bool hi = (t & 8) != 0;   // h=8 (DPP ror)
    float cs = __shfl(tc, j), sn = __shfl(tss, j);
    float s = hi ? -1.f : 1.f, csl = hi ? cs : 1.f, snl = hi ? sn : 0.f;
    dif_stepN<8, 24>(v, s, csl, snl); }
  { int j = (t & 3) << 3; bool hi = (t & 4) != 0;   // h=4 (shfl, LDS pipe)
    float cs = __shfl(tc, j), sn = __shfl(tss, j);
    float s = hi ? -1.f : 1.f, csl = hi ? cs : 1.f, snl = hi ? sn : 0.f;
    dif_stepN<4, 24>(v, s, csl, snl); }
  { bool hi = (t & 2) != 0, iq = (t & 1) != 0;      // h=2 (DPP)
    float s = hi ? -1.f : 1.f;
    float c2 = (hi && iq) ? 0.f : 1.f;
    float s2 = (hi && iq) ? (float)SIGN : 0.f;
    dif_stepN<2, 24>(v, s, c2, s2); }
  { bool hi = (t & 1) != 0;                          // h=1 (DPP, tw=1)
    dif_stepN_notw<1, 24>(v, hi ? -1.f : 1.f); }
}

template<int SIGN>
__device__ __forceinline__ void dit16x24(float2 v[24], int t, float tc, float tss) {
  { bool hi = (t & 1) != 0;
    dit_stepN_notw<1, 24>(v, hi ? -1.f : 1.f); }
  { bool hi = (t & 2) != 0, iq = (t & 1) != 0;
    float s = hi ? -1.f : 1.f;
    float c2 = (hi && iq) ? 0.f : 1.f;
    float s2 = (hi && iq) ? (float)SIGN : 0.f;
    dit_stepN<2, 24>(v, s, c2, s2); }
  { int j = (t & 3) << 3; bool hi = (t & 4) != 0;   // h=4 (shfl)
    float cs = __shfl(tc, j), sn = __shfl(tss, j);
    float s = hi ? -1.f : 1.f, csl = hi ? cs : 1.f, snl = hi ? sn : 0.f;
    dit_stepN<4, 24>(v, s, csl, snl); }
  { int j = (t & 7) << 2; bool hi = (t & 8) != 0;   // h=8 (DPP ror)
    float cs = __shfl(tc, j), sn = __shfl(tss, j);
    float s = hi ? -1.f : 1.f, csl = hi ? cs : 1.f, snl = hi ? sn : 0.f;
    dit_stepN<8, 24>(v, s, csl, snl); }
}

// FWD(24x16): v[r] = col[t16+16r] -> (t16,k1) holds X[k1 + 24*brev4(t16)].
// Twiddle W384^{SIGN*t*k1} = P[k1/6]*Q[k1%6].
template<int SIGN>
__device__ __forceinline__ void fwd384q(float2 v[24], int t16, float tc, float tss,
                                        const float2 Q[6], const float2 P[4]) {
  dft24<SIGN>(v);
#pragma unroll
  for (int k1 = 1; k1 < 24; ++k1) {
    int m = k1 / 6, q = k1 % 6;
    float2 x = v[k1];
    if (q) x = cmulf(x, Q[q]);
    if (m) x = cmulf(x, P[m]);
    v[k1] = x;
  }
  dif16x24<SIGN>(v, t16, tc, tss);
}

// BWD(24x16): exact inverse; P[m>=1] carry the 1/N scale, m==0 scales by inv.
template<int SIGN>
__device__ __forceinline__ void bwd384q(float2 v[24], int t16, float tc, float tss,
                                        const float2 Q[6], const float2 P[4],
                                        float inv) {
  dit16x24<SIGN>(v, t16, tc, tss);
#pragma unroll
  for (int k1 = 0; k1 < 24; ++k1) {
    int m = k1 / 6, q = k1 % 6;
    float2 x = v[k1];
    if (q) x = cmulf(x, Q[q]);
    if (m) x = cmulf(x, P[m]);
    else   x = make_float2(x.x * inv, x.y * inv);
    v[k1] = x;
  }
  dft24<SIGN>(v);
}

// ---------------- old LDS fft384 (precompute kernels only) -----------------
template<int R, int NS, int DIR>
__device__ __forceinline__ void fft_stage(const float2* S, float2* D, int t) {
  constexpr int NR = NN / R;
#pragma unroll
  for (int rep = 0; rep < (NR + 63) / 64; ++rep) {
    int j = t + rep * 64;
    if (j < NR) {
      float2 v[R];
#pragma unroll
      for (int r = 0; r < R; ++r) v[r] = S[LID(j + r * NR)];
      if constexpr (NS > 1) {
        float ang = (float)DIR * (TWOPI_F / (float)(NS * R)) * (float)(j % NS);
        float sv, cv;
        __sincosf(ang, &sv, &cv);
        float2 w = make_float2(cv, sv);
        float2 wr = w;
#pragma unroll
        for (int r = 1; r < R; ++r) { v[r] = cmulf(v[r], wr); wr = cmulf(wr, w); }
      }
      if constexpr (R == 4) dft4<DIR>(v); else dft6<DIR>(v);
      int base = (j / NS) * (NS * R) + (j % NS);
#pragma unroll
      for (int r = 0; r < R; ++r) D[LID(base + r * NS)] = v[r];
    }
  }
}

template<int DIR>
__device__ __forceinline__ void fft384(float2* A, float2* Bf, int t) {
  fft_stage<4, 1,  DIR>(A,  Bf, t); __syncthreads();
  fft_stage<4, 4,  DIR>(Bf, A,  t); __syncthreads();
  fft_stage<4, 16, DIR>(A,  Bf, t); __syncthreads();
  fft_stage<6, 64, DIR>(Bf, A,  t); __syncthreads();
}

// ---------------- E: iteration 1 (y0 = 0 -> xn = cz), elementwise ----------
__global__ __launch_bounds__(256) void k_e(const float2* __restrict__ czb,
                                           float2* __restrict__ xbuf,
                                           float2* __restrict__ ybuf) {
  long i = (long)blockIdx.x * 256 + threadIdx.x;
  float2 cz = czb[i];
  float2 x = make_float2(fmaxf(cz.x, 0.f), fmaxf(cz.y, 0.f));
  xbuf[i] = x;
  ybuf[i] = x;   // t1 = 1 -> y1 = x1
}

// ---------------- P1: row FFT of coil*y -> W1 (permuted-x storage) ---------
// grid B*C*384/4, 256 thr; one wave per row; no LDS, no barriers.
__global__ __launch_bounds__(256) void k_p1(const float2* __restrict__ ybuf,
                                            const float* __restrict__ csm,
                                            float2* __restrict__ W1) {
  int t = threadIdx.x & 63;
  int w = threadIdx.x >> 6;
  long gl = (long)blockIdx.x * 4 + w;       // (b*C + c)*384 + y
  int y = (int)(gl % NN);
  long bc = gl / NN;
  long b = bc >> 4, c = bc & 15;
  long rowoff = (long)y * NN;
  float tc, ts; __sincosf((float)(t & 31) * (PI_F / 32.0f), &ts, &tc);
  float tsf = -ts;                           // fwd (SIGN=-1) pre-signed
  float2 w0; __sincosf(-(float)t * (TWOPI_F / 384.0f), &w0.y, &w0.x);
  float2 wf[5];
  wf[0] = w0;
#pragma unroll
  for (int r = 1; r < 5; ++r) wf[r] = cmulf(wf[r - 1], w0);
  const float2* yrow = ybuf + b * (long)(NN * NN) + rowoff;
  const float* crow_re = csm + (b * 2 * CC + c) * (long)(NN * NN) + rowoff;
  const float* crow_im = crow_re + (long)CC * NN * NN;
  float2 v[6];
#pragma unroll
  for (int k = 0; k < 6; ++k) {
    int x = t + 64 * k;
    float2 yv = yrow[x];
    float cre = crow_re[x], cim = crow_im[x];
    v[k] = make_float2(yv.x * cre - yv.y * cim, yv.x * cim + yv.y * cre);
  }
  fwd384t<-1>(v, t, tc, tsf, wf);
  float2* orow = W1 + gl * NN;
#pragma unroll
  for (int r = 0; r < 6; ++r) orow[t + 64 * r] = v[r];
}

// ---------------- P2: col FFT -> mask -> col IFFT, in-place on W1 ----------
// grid B*C*(N/16)=1536 blocks, 256 thr. 16-col planar tile, pad 394
// (2*394 = 20 mod 32: fill/drain 2-way free; col reads <=3-way).
// Each 16-lane group (= one DPP row) owns one column, 24 regs deep.
// XCD-chunked swizzle. 1/N folded into bwd twiddles.
#define P2PAD 394
__global__ __launch_bounds__(256) void k_p2(float2* __restrict__ W1,
                                            const unsigned char* __restrict__ maskPT) {
  __shared__ float ldsR[16][P2PAD];
  __shared__ float ldsI[16][P2PAD];
  int tid = threadIdx.x;
  const int nwg = BB * CC * (NN / 16);           // 1536, divisible by 8
  int l = ((int)blockIdx.x & 7) * (nwg >> 3) + ((int)blockIdx.x >> 3);
  int xt = l % (NN / 16);
  long bc = l / (NN / 16);
  long b = bc >> 4;
  int s0 = xt * 16;
  long sbase = bc * (long)(NN * NN);
  int g = tid >> 4, t16 = tid & 15;
  int tl = tid & 63;
  // twiddle table (lane j of each wave holds cos/sin(pi*j/32))
  float tc, ts; __sincosf((float)(tl & 31) * (PI_F / 32.0f), &ts, &tc);
  float tsf = -ts;
  // W384^{t16*k1} power ladders (fwd sign -, bwd sign +)
  float2 w0; __sincosf(-(float)t16 * (TWOPI_F / 384.0f), &w0.y, &w0.x);
  float2 q2 = cmulf(w0, w0);
  float2 q3 = cmulf(q2, w0);
  float2 q4 = cmulf(q2, q2);
  float2 q5 = cmulf(q3, q2);
  float2 p1v = cmulf(q3, q3);     // w^6
  float2 p2v = cmulf(p1v, p1v);   // w^12
  float2 p3v = cmulf(p2v, p1v);   // w^18
  float2 Qf[6] = { make_float2(1.f, 0.f), w0, q2, q3, q4, q5 };
  float2 Pf[4] = { make_float2(1.f, 0.f), p1v, p2v, p3v };
  const float inv = 1.0f / NN;
  float2 Qb[6], Pb[4];
  Qb[0] = make_float2(1.f, 0.f);
#pragma unroll
  for (int i = 1; i < 6; ++i) Qb[i] = make_float2(Qf[i].x, -Qf[i].y);
  Pb[0] = make_float2(inv, 0.f);  // unused (m==0 path scales by inv)
#pragma unroll
  for (int m = 1; m < 4; ++m) Pb[m] = make_float2(Pf[m].x * inv, -Pf[m].y * inv);
  // fill: float4 (2 complex) per op; 8 float4 per row; 12 ops/thread
  const float4* W1v = (const float4*)W1;
  long f4base = (sbase >> 1) + (s0 >> 1);
#pragma unroll
  for (int k = 0; k < 12; ++k) {
    int e = tid + k * 256; int y = e >> 3; int q8 = e & 7;
    float4 val = W1v[f4base + (long)y * (NN / 2) + q8];
    ldsR[2 * q8][y] = val.x; ldsI[2 * q8][y] = val.y;
    ldsR[2 * q8 + 1][y] = val.z; ldsI[2 * q8 + 1][y] = val.w;
  }
  __syncthreads();
  {
    float2 v[24];
#pragma unroll
    for (int r = 0; r < 24; ++r)
      v[r] = make_float2(ldsR[g][t16 + 16 * r], ldsI[g][t16 + 16 * r]);
    fwd384q<-1>(v, t16, tc, tsf, Qf, Pf);
    // mask: freq at (t16,k1) = k1 + 24*brev4(t16); 6 x uchar4 loads
    int brt = (int)(__brev((unsigned)t16) >> 28);
    const unsigned char* mcol =
        maskPT + b * (long)(NN * NN) + (long)(s0 + g) * NN + 24 * brt;
#pragma unroll
    for (int i = 0; i < 6; ++i) {
      uchar4 mv = ((const uchar4*)mcol)[i];
      v[4 * i + 0].x *= (float)mv.x; v[4 * i + 0].y *= (float)mv.x;
      v[4 * i + 1].x *= (float)mv.y; v[4 * i + 1].y *= (float)mv.y;
      v[4 * i + 2].x *= (float)mv.z; v[4 * i + 2].y *= (float)mv.z;
      v[4 * i + 3].x *= (float)mv.w; v[4 * i + 3].y *= (float)mv.w;
    }
    bwd384q<1>(v, t16, tc, ts, Qb, Pb, inv);
#pragma unroll
    for (int r = 0; r < 24; ++r) {
      ldsR[g][t16 + 16 * r] = v[r].x;
      ldsI[g][t16 + 16 * r] = v[r].y;
    }
  }
  __syncthreads();
  float4* W1o = (float4*)W1;
#pragma unroll
  for (int k = 0; k < 12; ++k) {
    int e = tid + k * 256; int y = e >> 3; int q8 = e & 7;
    float4 val;
    val.x = ldsR[2 * q8][y]; val.y = ldsI[2 * q8][y];
    val.z = ldsR[2 * q8 + 1][y]; val.w = ldsI[2 * q8 + 1][y];
    W1o[f4base + (long)y * (NN / 2) + q8] = val;
  }
}

// ---------------- P3: row IFFT + conj(coil) reduce + FISTA update ----------
// grid B*384 blocks, 256 thr; wave w handles coils 4w..4w+3 (2 at a time);
// LDS reduce. Update: x = prox((1-lam)(y - Q) + cz).
// last!=0: write planar output instead of x/y (final iteration).
__global__ __launch_bounds__(256) void k_p3(const float2* __restrict__ W1,
                                            const float* __restrict__ csm,
                                            const float2* __restrict__ czb,
                                            const float* __restrict__ lamp,
                                            float2* __restrict__ xbuf,
                                            float2* __restrict__ ybuf,
                                            float* __restrict__ outp,
                                            float beta, int last) {
  __shared__ float2 part[4][NN];
  int tid = threadIdx.x;
  int w = tid >> 6, t = tid & 63;
  long gl = blockIdx.x;            // b*384 + y
  long b = gl / NN;
  int y = (int)(gl % NN);
  long rowoff = (long)y * NN;
  float tc, ts; __sincosf((float)(t & 31) * (PI_F / 32.0f), &ts, &tc);
  float2 w0; __sincosf((float)t * (TWOPI_F / 384.0f), &w0.y, &w0.x);
  float2 wb[5];
  wb[0] = w0;
#pragma unroll
  for (int r = 1; r < 5; ++r) wb[r] = cmulf(wb[r - 1], w0);
  float2 acc[6];
#pragma unroll
  for (int k = 0; k < 6; ++k) acc[k] = make_float2(0.f, 0.f);
#pragma unroll
  for (int ci = 0; ci < 4; ci += 2) {
    int c0 = w * 4 + ci, c1 = c0 + 1;
    const float2* row0 = W1 + ((b * CC + c0) * (long)NN + y) * NN;
    const float2* row1 = W1 + ((b * CC + c1) * (long)NN + y) * NN;
    float2 u[6], v[6];
#pragma unroll
    for (int r = 0; r < 6; ++r) { u[r] = row0[t + 64 * r]; v[r] = row1[t + 64 * r]; }
    bwd384t2<1>(u, v, t, tc, ts, wb, 1.0f);
    const float* cre0 = csm + (b * 2 * CC + c0) * (long)(NN * NN) + rowoff;
    const float* cim0 = cre0 + (long)CC * NN * NN;
    const float* cre1 = csm + (b * 2 * CC + c1) * (long)(NN * NN) + rowoff;
    const float* cim1 = cre1 + (long)CC * NN * NN;
#pragma unroll
    for (int k = 0; k < 6; ++k) {
      int x = t + 64 * k;
      float a0 = cre0[x], b0 = cim0[x];
      float a1 = cre1[x], b1 = cim1[x];
      acc[k].x += (a0 * u[k].x + b0 * u[k].y) + (a1 * v[k].x + b1 * v[k].y);
      acc[k].y += (a0 * u[k].y - b0 * u[k].x) + (a1 * v[k].y - b1 * v[k].x);
    }
  }
#pragma unroll
  for (int k = 0; k < 6; ++k) part[w][t + 64 * k] = acc[k];
  __syncthreads();
  float lamv = lamp[0];
  float oml = 1.0f - lamv;
  long pbase = b * (long)(NN * NN) + rowoff;
  for (int e = tid; e < NN; e += 256) {
    float Qx = (part[0][e].x + part[1][e].x + part[2][e].x + part[3][e].x) * (1.0f / NN);
    float Qy = (part[0][e].y + part[1][e].y + part[2][e].y + part[3][e].y) * (1.0f / NN);
    float2 yv = ybuf[pbase + e];
    float2 cz = czb[pbase + e];
    float xr = oml * (yv.x - Qx) + cz.x;
    float xi = oml * (yv.y - Qy) + cz.y;
    xr = fmaxf(xr, 0.f);
    xi = fmaxf(xi, 0.f);
    if (last) {
      outp[(b * 2 + 0) * (long)(NN * NN) + rowoff + e] = xr;
      outp[(b * 2 + 1) * (long)(NN * NN) + rowoff + e] = xi;
    } else {
      float2 xo = xbuf[pbase + e];
      xbuf[pbase + e] = make_float2(xr, xi);
      ybuf[pbase + e] = make_float2(xr + beta * (xr - xo.x), xi + beta * (xi - xo.y));
    }
  }
}

// ---------------- mask permutation precompute (one-time) -------------------
// maskPT[b][sx][y] = mask[b][y][P64(sx)], P64(s) = (s>>6) + 6*brev6(s&63).
__global__ __launch_bounds__(256) void k_mpre(const int* __restrict__ mask,
                                              unsigned char* __restrict__ maskPT) {
  long i = (long)blockIdx.x * 256 + threadIdx.x;
  long b = i / (NN * NN);
  int rem = (int)(i % (NN * NN));
  int sx = rem / NN, y = rem % NN;
  int fx = (sx >> 6) + 6 * (int)(__brev((unsigned)(sx & 63)) >> 26);
  maskPT[i] = (unsigned char)mask[b * (long)(NN * NN) + (long)y * NN + fx];
}

// ---------------- precompute: cz = (1-lam)*cst + lam*z ---------------------
__global__ __launch_bounds__(256) void k_preA(const float* __restrict__ x0,
                                              const int* __restrict__ mask,
                                              float2* __restrict__ T) {
  __shared__ float2 U[4][LNPAD], V[4][LNPAD];
  int tid = threadIdx.x;
  int line = tid >> 6, t = tid & 63;
  long gl0 = (long)blockIdx.x * 4;
#pragma unroll
  for (int k = 0; k < 6; ++k) {
    int e = tid + k * 256; int l = e / NN; int x = e % NN;
    long gl = gl0 + l;
    long b = gl / NN;
    int y = (int)(gl % NN);
    long pidx = (long)y * NN + x;
    float mv = (float)mask[b * (long)(NN * NN) + pidx];
    float br = x0[(b * 2 + 0) * (long)(NN * NN) + pidx] * mv;
    float bi = x0[(b * 2 + 1) * (long)(NN * NN) + pidx] * mv;
    U[l][LID(x)] = make_float2(br, bi);
  }
  __syncthreads();
  fft384<1>(U[line], V[line], t);
#pragma unroll
  for (int k = 0; k < 6; ++k) {
    int e = tid + k * 256; int l = e / NN; int x = e % NN;
    float2 u = U[l][LID(x)];
    T[(gl0 + l) * NN + x] = make_float2(u.x * (1.0f / NN), u.y * (1.0f / NN));
  }
}

__global__ __launch_bounds__(256) void k_preB(const float2* __restrict__ T,
                                              float2* __restrict__ r0) {
  __shared__ float2 tile[NN][17];
  __shared__ float2 U[4][LNPAD], V[4][LNPAD];
  int tid = threadIdx.x;
  int xt = blockIdx.x % (NN / 16);
  long b = blockIdx.x / (NN / 16);
  int x0c = xt * 16;
  long sbase = b * (long)(NN * NN);
#pragma unroll
  for (int k = 0; k < 24; ++k) {
    int e = tid + k * 256; int y = e >> 4; int c = e & 15;
    tile[y][c] = T[sbase + (long)y * NN + x0c + c];
  }
  __syncthreads();
  int line = tid >> 6, t = tid & 63;
  for (int g = 0; g < 4; ++g) {
#pragma unroll
    for (int k = 0; k < 6; ++k) {
      int e = tid + k * 256; int l = e / NN; int y = e % NN;
      U[l][LID(y)] = tile[y][4 * g + l];
    }
    __syncthreads();
    fft384<1>(U[line], V[line], t);
#pragma unroll
    for (int k = 0; k < 6; ++k) {
      int e = tid + k * 256; int l = e / NN; int y = e % NN;
      float2 u = U[l][LID(y)];
      tile[y][4 * g + l] = make_float2(u.x * (1.0f / NN), u.y * (1.0f / NN));
    }
    __syncthreads();
  }
#pragma unroll
  for (int k = 0; k < 24; ++k) {
    int e = tid + k * 256; int y = e >> 4; int c = e & 15;
    r0[sbase + (long)y * NN + x0c + c] = tile[y][c];
  }
}

__global__ __launch_bounds__(256) void k_preC(const float* __restrict__ csm,
                                              const float2* __restrict__ r0,
                                              const float* __restrict__ zk,
                                              const float* __restrict__ lamp,
                                              float2* __restrict__ czb) {
  long i = (long)blockIdx.x * 256 + threadIdx.x;
  long b = i / (NN * NN);
  long p = i % (NN * NN);
  float sr = 0.f, si = 0.f;
#pragma unroll
  for (int c = 0; c < CC; ++c) {
    sr += csm[(b * 2 * CC + c) * (long)(NN * NN) + p];
    si -= csm[((b * 2 + 1) * CC + c) * (long)(NN * NN) + p];
  }
  float2 r = r0[i];
  float cstx = sr * r.x - si * r.y;
  float csty = sr * r.y + si * r.x;
  float lamv = lamp[0];
  float oml = 1.0f - lamv;
  float zr = zk[(b * 2 + 0) * (long)(NN * NN) + p];
  float zi = zk[(b * 2 + 1) * (long)(NN * NN) + p];
  czb[i] = make_float2(oml * cstx + lamv * zr, oml * csty + lamv * zi);
}

extern "C" void kernel_launch(void* const* d_in, const int* in_sizes, int n_in,
                              void* d_out, int out_size, void* d_ws, size_t ws_size,
                              hipStream_t stream) {
  const float* zk  = (const float*)d_in[0];
  const float* x0  = (const float*)d_in[1];
  const float* csm = (const float*)d_in[2];
  const float* lam = (const float*)d_in[3];
  const int*   msk = (const int*)d_in[4];
  float* out = (float*)d_out;

  // ws layout (float2 units): W1 [B*C*N*N] | y | x | cz | maskPT(uchar)
  size_t img = (size_t)BB * NN * NN;
  float2* W1   = (float2*)d_ws;
  float2* ybuf = W1 + (size_t)BB * CC * NN * NN;
  float2* xbuf = ybuf + img;
  float2* czb  = xbuf + img;
  unsigned char* maskPT = (unsigned char*)(czb + img);
  float2* T  = W1;        // precompute scratch overlays W1
  float2* r0 = W1 + img;

  double tcur = 1.0;
  float betas[NITER];
  for (int i = 0; i < NITER; ++i) {
    double tn = (1.0 + sqrt(1.0 + 4.0 * tcur * tcur)) * 0.5;
    betas[i] = (float)((tcur - 1.0) / tn);
    tcur = tn;
  }

  k_mpre<<<(BB * NN * NN) / 256, 256, 0, stream>>>(msk, maskPT);
  k_preA<<<BB * NN / 4, 256, 0, stream>>>(x0, msk, T);
  k_preB<<<BB * (NN / 16), 256, 0, stream>>>(T, r0);
  k_preC<<<(BB * NN * NN) / 256, 256, 0, stream>>>(csm, r0, zk, lam, czb);
  // iteration 1 (y0 = 0): x1 = prox(cz)
  k_e<<<(BB * NN * NN) / 256, 256, 0, stream>>>(czb, xbuf, ybuf);
  // iterations 2..20: forward, mask round-trip, adjoint+update
  for (int i = 1; i < NITER; ++i) {
    k_p1<<<BB * CC * NN / 4, 256, 0, stream>>>(ybuf, csm, W1);
    k_p2<<<BB * CC * (NN / 16), 256, 0, stream>>>(W1, maskPT);
    k_p3<<<BB * NN, 256, 0, stream>>>(W1, csm, czb, lam, xbuf, ybuf, out,
                                      betas[i], (i == NITER - 1) ? 1 : 0);
  }
}

// Round 20
// 1828.770 us; speedup vs baseline: 1.2328x; 1.0041x over previous
//
#include <hip/hip_runtime.h>
#include <math.h>

// FISTA data-consistency with masked multi-coil 2D FFT operator.
// B=4, C=16, H=W=384.
// p1: register FFT 384 = 6 regs x 64 lanes. p2: 384 = 24 regs x 16 lanes
// (R18 form: 256 thr, 16-col tile, PAD=394). p3 (R19): all 4 coils
// interleaved through ONE FFT body (q[4][6], compile-time indices) — 4x
// exchange-chain ILP; summation order preserved -> absmax bit-exact.
// Exchanges: h=1,2 DPP quad_perm; h=8 DPP row_ror:8; h=4,16,32 __shfl_xor.
// Butterflies fma/fold. zk folded out (cz); 1/N folded into twiddles.
// R8: fp16 W1 FAILS (range). bf16 csm REJECTED (0.4%x19 apps ~ 15% >> 2%).
// R9: builtins only. R14: permlane builtin ~5 VALU ops. R15: no 4-col ILP
// in p2's LDS-tile fill (bank conflicts); p3 has no such tile.

#define NN 384
#define BB 4
#define CC 16
#define NITER 20
#define LNPAD 432   // old LDS path (precompute only)
#define PI_F 3.14159265358979323846f
#define TWOPI_F 6.28318530717958647692f

__device__ __forceinline__ int LID(int i) { return i + (i >> 3); }

__device__ __forceinline__ float2 cmulf(float2 a, float2 b) {
  return make_float2(a.x * b.x - a.y * b.y, a.x * b.y + a.y * b.x);
}

// ---------------- cross-lane exchange primitives ---------------------------
template<int CTRL>
__device__ __forceinline__ float dppx(float v) {
  int s = __float_as_int(v);
  return __int_as_float(__builtin_amdgcn_update_dpp(s, s, CTRL, 0xF, 0xF, true));
}

template<int H>
__device__ __forceinline__ float2 exch(float2 v) {
  if constexpr (H == 1) {
    return make_float2(dppx<0xB1>(v.x), dppx<0xB1>(v.y));   // quad [1,0,3,2]
  } else if constexpr (H == 2) {
    return make_float2(dppx<0x4E>(v.x), dppx<0x4E>(v.y));   // quad [2,3,0,1]
  } else if constexpr (H == 8) {
    return make_float2(dppx<0x128>(v.x), dppx<0x128>(v.y)); // row_ror:8
  } else {
    return make_float2(__shfl_xor(v.x, H), __shfl_xor(v.y, H));
  }
}

template<int DIR>
__device__ __forceinline__ void dft4(float2* v) {
  float ax = v[0].x + v[2].x, ay = v[0].y + v[2].y;
  float bx = v[0].x - v[2].x, by = v[0].y - v[2].y;
  float cx = v[1].x + v[3].x, cy = v[1].y + v[3].y;
  float dx = v[1].x - v[3].x, dy = v[1].y - v[3].y;
  float dix, diy;
  if (DIR < 0) { dix = dy; diy = -dx; }
  else         { dix = -dy; diy = dx; }
  v[0] = make_float2(ax + cx, ay + cy);
  v[2] = make_float2(ax - cx, ay - cy);
  v[1] = make_float2(bx + dix, by + diy);
  v[3] = make_float2(bx - dix, by - diy);
}

// DFT-3: X1 = m + i*s*S3*d, X2 = m - i*s*S3*d; m = a - u/2, u=b+c, d=b-c.
template<int SIGN>
__device__ __forceinline__ void dft3(float2 a, float2 b, float2 c,
                                     float2& X0, float2& X1, float2& X2) {
  const float S3 = 0.86602540378443864676f;
  float ux = b.x + c.x, uy = b.y + c.y;
  float dx = b.x - c.x, dy = b.y - c.y;
  float mx = a.x - 0.5f * ux, my = a.y - 0.5f * uy;
  float ex = S3 * dx, ey = S3 * dy;
  X0 = make_float2(a.x + ux, a.y + uy);
  if (SIGN < 0) {
    X1 = make_float2(mx + ey, my - ex);
    X2 = make_float2(mx - ey, my + ex);
  } else {
    X1 = make_float2(mx - ey, my + ex);
    X2 = make_float2(mx + ey, my - ex);
  }
}

// Fast DFT-6 = two DFT-3 + trivial W6 twiddles. Verified on impulses.
template<int SIGN>
__device__ __forceinline__ void dft6(float2* v) {
  const float S3 = 0.86602540378443864676f;
  float2 E0, E1, E2, O0, O1, O2;
  dft3<SIGN>(v[0], v[2], v[4], E0, E1, E2);
  dft3<SIGN>(v[1], v[3], v[5], O0, O1, O2);
  const float ss = (SIGN < 0) ? -S3 : S3;
  float2 T1 = cmulf(O1, make_float2(0.5f, ss));
  float2 T2 = cmulf(O2, make_float2(-0.5f, ss));
  v[0] = make_float2(E0.x + O0.x, E0.y + O0.y);
  v[1] = make_float2(E1.x + T1.x, E1.y + T1.y);
  v[2] = make_float2(E2.x + T2.x, E2.y + T2.y);
  v[3] = make_float2(E0.x - O0.x, E0.y - O0.y);
  v[4] = make_float2(E1.x - T1.x, E1.y - T1.y);
  v[5] = make_float2(E2.x - T2.x, E2.y - T2.y);
}

// W24^{sign*j}, j in [0,16). Compile-time folded.
__device__ __forceinline__ float2 w24v(int j, int sign) {
  constexpr float C[16] = {
    1.f, 0.96592582628906831f, 0.86602540378443865f, 0.70710678118654752f,
    0.5f, 0.25881904510252076f, 0.f, -0.25881904510252076f,
    -0.5f, -0.70710678118654752f, -0.86602540378443865f, -0.96592582628906831f,
    -1.f, -0.96592582628906831f, -0.86602540378443865f, -0.70710678118654752f };
  constexpr float S[16] = {
    0.f, 0.25881904510252076f, 0.5f, 0.70710678118654752f,
    0.86602540378443865f, 0.96592582628906831f, 1.f, 0.96592582628906831f,
    0.86602540378443865f, 0.70710678118654752f, 0.5f, 0.25881904510252076f,
    0.f, -0.25881904510252076f, -0.5f, -0.70710678118654752f };
  return make_float2(C[j], sign < 0 ? -S[j] : S[j]);
}

// DFT-24 over registers: 24 = 4(a) x 6(b), x[a+4b]. Impulse-verified.
template<int SIGN>
__device__ __forceinline__ void dft24(float2 v[24]) {
#pragma unroll
  for (int a = 0; a < 4; ++a) {
    float2 tmp[6];
#pragma unroll
    for (int b = 0; b < 6; ++b) tmp[b] = v[a + 4 * b];
    dft6<SIGN>(tmp);
#pragma unroll
    for (int k6 = 0; k6 < 6; ++k6) v[a + 4 * k6] = tmp[k6];
  }
  float2 o[24];
#pragma unroll
  for (int k6 = 0; k6 < 6; ++k6) {
    float2 h[4];
    h[0] = v[4 * k6];
#pragma unroll
    for (int a = 1; a < 4; ++a) {
      int j = a * k6;
      h[a] = (j == 0) ? v[a + 4 * k6] : cmulf(v[a + 4 * k6], w24v(j, SIGN));
    }
    dft4<SIGN>(h);
#pragma unroll
    for (int m = 0; m < 4; ++m) o[k6 + 6 * m] = h[m];
  }
#pragma unroll
  for (int i = 0; i < 24; ++i) v[i] = o[i];
}

// ---------------- generic butterfly steps (NR registers) -------------------
template<int H, int NR>
__device__ __forceinline__ void dif_stepN(float2* v, float s, float csl, float snl) {
#pragma unroll
  for (int r = 0; r < NR; ++r) {
    float2 o = exch<H>(v[r]);
    float dx = fmaf(s, v[r].x, o.x);
    float dy = fmaf(s, v[r].y, o.y);
    v[r] = make_float2(dx * csl - dy * snl, dx * snl + dy * csl);
  }
}
template<int H, int NR>
__device__ __forceinline__ void dif_stepN_notw(float2* v, float s) {
#pragma unroll
  for (int r = 0; r < NR; ++r) {
    float2 o = exch<H>(v[r]);
    v[r] = make_float2(fmaf(s, v[r].x, o.x), fmaf(s, v[r].y, o.y));
  }
}
template<int H, int NR>
__device__ __forceinline__ void dit_stepN(float2* v, float s, float csl, float snl) {
#pragma unroll
  for (int r = 0; r < NR; ++r) {
    float2 bt = make_float2(v[r].x * csl - v[r].y * snl,
                            v[r].x * snl + v[r].y * csl);
    float2 o = exch<H>(bt);
    v[r] = make_float2(fmaf(s, bt.x, o.x), fmaf(s, bt.y, o.y));
  }
}
template<int H, int NR>
__device__ __forceinline__ void dit_stepN_notw(float2* v, float s) {
#pragma unroll
  for (int r = 0; r < NR; ++r) {
    float2 o = exch<H>(v[r]);
    v[r] = make_float2(fmaf(s, v[r].x, o.x), fmaf(s, v[r].y, o.y));
  }
}

// ---------------- 64-lane FFT drivers ----------------------
template<int SIGN>
__device__ __forceinline__ void dif64t(float2 v[6], int t, float tc, float tss) {
  { int j = t & 31; bool hi = (t & 32) != 0;
    float cs = __shfl(tc, j), sn = __shfl(tss, j);
    float s = hi ? -1.f : 1.f, csl = hi ? cs : 1.f, snl = hi ? sn : 0.f;
    dif_stepN<32, 6>(v, s, csl, snl); }
  { int j = (t & 15) << 1; bool hi = (t & 16) != 0;
    float cs = __shfl(tc, j), sn = __shfl(tss, j);
    float s = hi ? -1.f : 1.f, csl = hi ? cs : 1.f, snl = hi ? sn : 0.f;
    dif_stepN<16, 6>(v, s, csl, snl); }
  { int j = (t & 7) << 2; bool hi = (t & 8) != 0;
    float cs = __shfl(tc, j), sn = __shfl(tss, j);
    float s = hi ? -1.f : 1.f, csl = hi ? cs : 1.f, snl = hi ? sn : 0.f;
    dif_stepN<8, 6>(v, s, csl, snl); }
  { int j = (t & 3) << 3; bool hi = (t & 4) != 0;
    float cs = __shfl(tc, j), sn = __shfl(tss, j);
    float s = hi ? -1.f : 1.f, csl = hi ? cs : 1.f, snl = hi ? sn : 0.f;
    dif_stepN<4, 6>(v, s, csl, snl); }
  { bool hi = (t & 2) != 0, iq = (t & 1) != 0;
    float s = hi ? -1.f : 1.f;
    float c2 = (hi && iq) ? 0.f : 1.f;
    float s2 = (hi && iq) ? (float)SIGN : 0.f;
    dif_stepN<2, 6>(v, s, c2, s2); }
  { bool hi = (t & 1) != 0;
    dif_stepN_notw<1, 6>(v, hi ? -1.f : 1.f); }
}

// 4-coil interleaved DIT (p3): q[4][6], all indices compile-time.
template<int SIGN>
__device__ __forceinline__ void dit64t4(float2 q[4][6], int t,
                                        float tc, float tss) {
  { bool hi = (t & 1) != 0;
    float s = hi ? -1.f : 1.f;
#pragma unroll
    for (int c = 0; c < 4; ++c) dit_stepN_notw<1, 6>(q[c], s); }
  { bool hi = (t & 2) != 0, iq = (t & 1) != 0;
    float s = hi ? -1.f : 1.f;
    float c2 = (hi && iq) ? 0.f : 1.f;
    float s2 = (hi && iq) ? (float)SIGN : 0.f;
#pragma unroll
    for (int c = 0; c < 4; ++c) dit_stepN<2, 6>(q[c], s, c2, s2); }
  { int j = (t & 3) << 3; bool hi = (t & 4) != 0;
    float cs = __shfl(tc, j), sn = __shfl(tss, j);
    float s = hi ? -1.f : 1.f, csl = hi ? cs : 1.f, snl = hi ? sn : 0.f;
#pragma unroll
    for (int c = 0; c < 4; ++c) dit_stepN<4, 6>(q[c], s, csl, snl); }
  { int j = (t & 7) << 2; bool hi = (t & 8) != 0;
    float cs = __shfl(tc, j), sn = __shfl(tss, j);
    float s = hi ? -1.f : 1.f, csl = hi ? cs : 1.f, snl = hi ? sn : 0.f;
#pragma unroll
    for (int c = 0; c < 4; ++c) dit_stepN<8, 6>(q[c], s, csl, snl); }
  { int j = (t & 15) << 1; bool hi = (t & 16) != 0;
    float cs = __shfl(tc, j), sn = __shfl(tss, j);
    float s = hi ? -1.f : 1.f, csl = hi ? cs : 1.f, snl = hi ? sn : 0.f;
#pragma unroll
    for (int c = 0; c < 4; ++c) dit_stepN<16, 6>(q[c], s, csl, snl); }
  { int j = t & 31; bool hi = (t & 32) != 0;
    float cs = __shfl(tc, j), sn = __shfl(tss, j);
    float s = hi ? -1.f : 1.f, csl = hi ? cs : 1.f, snl = hi ? sn : 0.f;
#pragma unroll
    for (int c = 0; c < 4; ++c) dit_stepN<32, 6>(q[c], s, csl, snl); }
}

template<int SIGN>
__device__ __forceinline__ void fwd384t(float2 v[6], int t, float tc, float tss,
                                        const float2 w[5]) {
  dft6<SIGN>(v);
#pragma unroll
  for (int r = 1; r < 6; ++r) v[r] = cmulf(v[r], w[r - 1]);
  dif64t<SIGN>(v, t, tc, tss);
}

// BWD quad (p3): permuted in -> natural out (unnormalized).
template<int SIGN>
__device__ __forceinline__ void bwd384t4(float2 q[4][6], int t,
                                         float tc, float tss, const float2 w[5]) {
  dit64t4<SIGN>(q, t, tc, tss);
#pragma unroll
  for (int c = 0; c < 4; ++c) {
#pragma unroll
    for (int r = 1; r < 6; ++r) q[c][r] = cmulf(q[c][r], w[r - 1]);
    dft6<SIGN>(q[c]);
  }
}

// ---------------- 16-lane FFT drivers (p2, 24 regs) ------------------------
template<int SIGN>
__device__ __forceinline__ void dif16x24(float2 v[24], int t, float tc, float tss) {
  { int j = (t & 7) << 2; bool hi = (t & 8) != 0;   // h=8 (DPP ror)
    float cs = __shfl(tc, j), sn = __shfl(tss, j);
    float s = hi ? -1.f : 1.f, csl = hi ? cs : 1.f, snl = hi ? sn : 0.f;
    dif_stepN<8, 24>(v, s, csl, snl); }
  { int j = (t & 3) << 3; bool hi = (t & 4) != 0;   // h=4 (shfl, LDS pipe)
    float cs = __shfl(tc, j), sn = __shfl(tss, j);
    float s = hi ? -1.f : 1.f, csl = hi ? cs : 1.f, snl = hi ? sn : 0.f;
    dif_stepN<4, 24>(v, s, csl, snl); }
  { bool hi = (t & 2) != 0, iq = (t & 1) != 0;      // h=2 (DPP)
    float s = hi ? -1.f : 1.f;
    float c2 = (hi && iq) ? 0.f : 1.f;
    float s2 = (hi && iq) ? (float)SIGN : 0.f;
    dif_stepN<2, 24>(v, s, c2, s2); }
  { bool hi = (t & 1) != 0;                          // h=1 (DPP, tw=1)
    dif_stepN_notw<1, 24>(v, hi ? -1.f : 1.f); }
}

template<int SIGN>
__device__ __forceinline__ void dit16x24(float2 v[24], int t, float tc, float tss) {
  { bool hi = (t & 1) != 0;
    dit_stepN_notw<1, 24>(v, hi ? -1.f : 1.f); }
  { bool hi = (t & 2) != 0, iq = (t & 1) != 0;
    float s = hi ? -1.f : 1.f;
    float c2 = (hi && iq) ? 0.f : 1.f;
    float s2 = (hi && iq) ? (float)SIGN : 0.f;
    dit_stepN<2, 24>(v, s, c2, s2); }
  { int j = (t & 3) << 3; bool hi = (t & 4) != 0;   // h=4 (shfl)
    float cs = __shfl(tc, j), sn = __shfl(tss, j);
    float s = hi ? -1.f : 1.f, csl = hi ? cs : 1.f, snl = hi ? sn : 0.f;
    dit_stepN<4, 24>(v, s, csl, snl); }
  { int j = (t & 7) << 2; bool hi = (t & 8) != 0;   // h=8 (DPP ror)
    float cs = __shfl(tc, j), sn = __shfl(tss, j);
    float s = hi ? -1.f : 1.f, csl = hi ? cs : 1.f, snl = hi ? sn : 0.f;
    dit_stepN<8, 24>(v, s, csl, snl); }
}

// FWD(24x16): (t16,k1) holds X[k1 + 24*brev4(t16)]. W384^{t*k1}=P[k1/6]*Q[k1%6].
template<int SIGN>
__device__ __forceinline__ void fwd384q(float2 v[24], int t16, float tc, float tss,
                                        const float2 Q[6], const float2 P[4]) {
  dft24<SIGN>(v);
#pragma unroll
  for (int k1 = 1; k1 < 24; ++k1) {
    int m = k1 / 6, q = k1 % 6;
    float2 x = v[k1];
    if (q) x = cmulf(x, Q[q]);
    if (m) x = cmulf(x, P[m]);
    v[k1] = x;
  }
  dif16x24<SIGN>(v, t16, tc, tss);
}

// BWD(24x16): exact inverse; P[m>=1] carry the 1/N scale, m==0 scales by inv.
template<int SIGN>
__device__ __forceinline__ void bwd384q(float2 v[24], int t16, float tc, float tss,
                                        const float2 Q[6], const float2 P[4],
                                        float inv) {
  dit16x24<SIGN>(v, t16, tc, tss);
#pragma unroll
  for (int k1 = 0; k1 < 24; ++k1) {
    int m = k1 / 6, q = k1 % 6;
    float2 x = v[k1];
    if (q) x = cmulf(x, Q[q]);
    if (m) x = cmulf(x, P[m]);
    else   x = make_float2(x.x * inv, x.y * inv);
    v[k1] = x;
  }
  dft24<SIGN>(v);
}

// ---------------- old LDS fft384 (precompute kernels only) -----------------
template<int R, int NS, int DIR>
__device__ __forceinline__ void fft_stage(const float2* S, float2* D, int t) {
  constexpr int NR = NN / R;
#pragma unroll
  for (int rep = 0; rep < (NR + 63) / 64; ++rep) {
    int j = t + rep * 64;
    if (j < NR) {
      float2 v[R];
#pragma unroll
      for (int r = 0; r < R; ++r) v[r] = S[LID(j + r * NR)];
      if constexpr (NS > 1) {
        float ang = (float)DIR * (TWOPI_F / (float)(NS * R)) * (float)(j % NS);
        float sv, cv;
        __sincosf(ang, &sv, &cv);
        float2 w = make_float2(cv, sv);
        float2 wr = w;
#pragma unroll
        for (int r = 1; r < R; ++r) { v[r] = cmulf(v[r], wr); wr = cmulf(wr, w); }
      }
      if constexpr (R == 4) dft4<DIR>(v); else dft6<DIR>(v);
      int base = (j / NS) * (NS * R) + (j % NS);
#pragma unroll
      for (int r = 0; r < R; ++r) D[LID(base + r * NS)] = v[r];
    }
  }
}

template<int DIR>
__device__ __forceinline__ void fft384(float2* A, float2* Bf, int t) {
  fft_stage<4, 1,  DIR>(A,  Bf, t); __syncthreads();
  fft_stage<4, 4,  DIR>(Bf, A,  t); __syncthreads();
  fft_stage<4, 16, DIR>(A,  Bf, t); __syncthreads();
  fft_stage<6, 64, DIR>(Bf, A,  t); __syncthreads();
}

// ---------------- E: iteration 1 (y0 = 0 -> xn = cz), elementwise ----------
__global__ __launch_bounds__(256) void k_e(const float2* __restrict__ czb,
                                           float2* __restrict__ xbuf,
                                           float2* __restrict__ ybuf) {
  long i = (long)blockIdx.x * 256 + threadIdx.x;
  float2 cz = czb[i];
  float2 x = make_float2(fmaxf(cz.x, 0.f), fmaxf(cz.y, 0.f));
  xbuf[i] = x;
  ybuf[i] = x;   // t1 = 1 -> y1 = x1
}

// ---------------- P1: row FFT of coil*y -> W1 (permuted-x storage) ---------
// grid B*C*384/4, 256 thr; one wave per row; no LDS, no barriers.
__global__ __launch_bounds__(256) void k_p1(const float2* __restrict__ ybuf,
                                            const float* __restrict__ csm,
                                            float2* __restrict__ W1) {
  int t = threadIdx.x & 63;
  int w = threadIdx.x >> 6;
  long gl = (long)blockIdx.x * 4 + w;       // (b*C + c)*384 + y
  int y = (int)(gl % NN);
  long bc = gl / NN;
  long b = bc >> 4, c = bc & 15;
  long rowoff = (long)y * NN;
  float tc, ts; __sincosf((float)(t & 31) * (PI_F / 32.0f), &ts, &tc);
  float tsf = -ts;                           // fwd (SIGN=-1) pre-signed
  float2 w0; __sincosf(-(float)t * (TWOPI_F / 384.0f), &w0.y, &w0.x);
  float2 wf[5];
  wf[0] = w0;
#pragma unroll
  for (int r = 1; r < 5; ++r) wf[r] = cmulf(wf[r - 1], w0);
  const float2* yrow = ybuf + b * (long)(NN * NN) + rowoff;
  const float* crow_re = csm + (b * 2 * CC + c) * (long)(NN * NN) + rowoff;
  const float* crow_im = crow_re + (long)CC * NN * NN;
  float2 v[6];
#pragma unroll
  for (int k = 0; k < 6; ++k) {
    int x = t + 64 * k;
    float2 yv = yrow[x];
    float cre = crow_re[x], cim = crow_im[x];
    v[k] = make_float2(yv.x * cre - yv.y * cim, yv.x * cim + yv.y * cre);
  }
  fwd384t<-1>(v, t, tc, tsf, wf);
  float2* orow = W1 + gl * NN;
#pragma unroll
  for (int r = 0; r < 6; ++r) orow[t + 64 * r] = v[r];
}

// ---------------- P2: col FFT -> mask -> col IFFT, in-place on W1 ----------
// grid B*C*(N/16)=1536 blocks, 256 thr. 16-col planar tile, pad 394.
// Each 16-lane group owns one column, 24 regs deep. XCD swizzle.
#define P2PAD 394
__global__ __launch_bounds__(256) void k_p2(float2* __restrict__ W1,
                                            const unsigned char* __restrict__ maskPT) {
  __shared__ float ldsR[16][P2PAD];
  __shared__ float ldsI[16][P2PAD];
  int tid = threadIdx.x;
  const int nwg = BB * CC * (NN / 16);           // 1536, divisible by 8
  int l = ((int)blockIdx.x & 7) * (nwg >> 3) + ((int)blockIdx.x >> 3);
  int xt = l % (NN / 16);
  long bc = l / (NN / 16);
  long b = bc >> 4;
  int s0 = xt * 16;
  long sbase = bc * (long)(NN * NN);
  int g = tid >> 4, t16 = tid & 15;
  int tl = tid & 63;
  float tc, ts; __sincosf((float)(tl & 31) * (PI_F / 32.0f), &ts, &tc);
  float tsf = -ts;
  float2 w0; __sincosf(-(float)t16 * (TWOPI_F / 384.0f), &w0.y, &w0.x);
  float2 q2 = cmulf(w0, w0);
  float2 q3 = cmulf(q2, w0);
  float2 q4 = cmulf(q2, q2);
  float2 q5 = cmulf(q3, q2);
  float2 p1v = cmulf(q3, q3);     // w^6
  float2 p2v = cmulf(p1v, p1v);   // w^12
  float2 p3v = cmulf(p2v, p1v);   // w^18
  float2 Qf[6] = { make_float2(1.f, 0.f), w0, q2, q3, q4, q5 };
  float2 Pf[4] = { make_float2(1.f, 0.f), p1v, p2v, p3v };
  const float inv = 1.0f / NN;
  float2 Qb[6], Pb[4];
  Qb[0] = make_float2(1.f, 0.f);
#pragma unroll
  for (int i = 1; i < 6; ++i) Qb[i] = make_float2(Qf[i].x, -Qf[i].y);
  Pb[0] = make_float2(inv, 0.f);  // unused (m==0 path scales by inv)
#pragma unroll
  for (int m = 1; m < 4; ++m) Pb[m] = make_float2(Pf[m].x * inv, -Pf[m].y * inv);
  const float4* W1v = (const float4*)W1;
  long f4base = (sbase >> 1) + (s0 >> 1);
#pragma unroll
  for (int k = 0; k < 12; ++k) {
    int e = tid + k * 256; int y = e >> 3; int q8 = e & 7;
    float4 val = W1v[f4base + (long)y * (NN / 2) + q8];
    ldsR[2 * q8][y] = val.x; ldsI[2 * q8][y] = val.y;
    ldsR[2 * q8 + 1][y] = val.z; ldsI[2 * q8 + 1][y] = val.w;
  }
  __syncthreads();
  {
    float2 v[24];
#pragma unroll
    for (int r = 0; r < 24; ++r)
      v[r] = make_float2(ldsR[g][t16 + 16 * r], ldsI[g][t16 + 16 * r]);
    fwd384q<-1>(v, t16, tc, tsf, Qf, Pf);
    int brt = (int)(__brev((unsigned)t16) >> 28);
    const unsigned char* mcol =
        maskPT + b * (long)(NN * NN) + (long)(s0 + g) * NN + 24 * brt;
#pragma unroll
    for (int i = 0; i < 6; ++i) {
      uchar4 mv = ((const uchar4*)mcol)[i];
      v[4 * i + 0].x *= (float)mv.x; v[4 * i + 0].y *= (float)mv.x;
      v[4 * i + 1].x *= (float)mv.y; v[4 * i + 1].y *= (float)mv.y;
      v[4 * i + 2].x *= (float)mv.z; v[4 * i + 2].y *= (float)mv.z;
      v[4 * i + 3].x *= (float)mv.w; v[4 * i + 3].y *= (float)mv.w;
    }
    bwd384q<1>(v, t16, tc, ts, Qb, Pb, inv);
#pragma unroll
    for (int r = 0; r < 24; ++r) {
      ldsR[g][t16 + 16 * r] = v[r].x;
      ldsI[g][t16 + 16 * r] = v[r].y;
    }
  }
  __syncthreads();
  float4* W1o = (float4*)W1;
#pragma unroll
  for (int k = 0; k < 12; ++k) {
    int e = tid + k * 256; int y = e >> 3; int q8 = e & 7;
    float4 val;
    val.x = ldsR[2 * q8][y]; val.y = ldsI[2 * q8][y];
    val.z = ldsR[2 * q8 + 1][y]; val.w = ldsI[2 * q8 + 1][y];
    W1o[f4base + (long)y * (NN / 2) + q8] = val;
  }
}

// ---------------- P3: row IFFT + conj(coil) reduce + FISTA update ----------
// grid B*384 blocks, 256 thr; wave w handles coils 4w..4w+3, all FOUR
// interleaved through one FFT body (R19); LDS reduce.
// Summation order preserved vs R18 -> absmax bit-exact.
__global__ __launch_bounds__(256) void k_p3(const float2* __restrict__ W1,
                                            const float* __restrict__ csm,
                                            const float2* __restrict__ czb,
                                            const float* __restrict__ lamp,
                                            float2* __restrict__ xbuf,
                                            float2* __restrict__ ybuf,
                                            float* __restrict__ outp,
                                            float beta, int last) {
  __shared__ float2 part[4][NN];
  int tid = threadIdx.x;
  int w = tid >> 6, t = tid & 63;
  long gl = blockIdx.x;            // b*384 + y
  long b = gl / NN;
  int y = (int)(gl % NN);
  long rowoff = (long)y * NN;
  float tc, ts; __sincosf((float)(t & 31) * (PI_F / 32.0f), &ts, &tc);
  float2 w0; __sincosf((float)t * (TWOPI_F / 384.0f), &w0.y, &w0.x);
  float2 wb[5];
  wb[0] = w0;
#pragma unroll
  for (int r = 1; r < 5; ++r) wb[r] = cmulf(wb[r - 1], w0);
  int c0 = w * 4;
  float2 q[4][6];
#pragma unroll
  for (int c = 0; c < 4; ++c) {
    const float2* row = W1 + ((b * CC + c0 + c) * (long)NN + y) * NN;
#pragma unroll
    for (int r = 0; r < 6; ++r) q[c][r] = row[t + 64 * r];
  }
  bwd384t4<1>(q, t, tc, ts, wb);
  float2 acc[6];
#pragma unroll
  for (int k = 0; k < 6; ++k) acc[k] = make_float2(0.f, 0.f);
#pragma unroll
  for (int cp = 0; cp < 2; ++cp) {
    int ca = c0 + 2 * cp, cb2 = ca + 1;
    const float* creA = csm + (b * 2 * CC + ca) * (long)(NN * NN) + rowoff;
    const float* cimA = creA + (long)CC * NN * NN;
    const float* creB = csm + (b * 2 * CC + cb2) * (long)(NN * NN) + rowoff;
    const float* cimB = creB + (long)CC * NN * NN;
#pragma unroll
    for (int k = 0; k < 6; ++k) {
      int x = t + 64 * k;
      float a0 = creA[x], b0 = cimA[x];
      float a1 = creB[x], b1 = cimB[x];
      float2 u = q[2 * cp][k], v = q[2 * cp + 1][k];
      acc[k].x += (a0 * u.x + b0 * u.y) + (a1 * v.x + b1 * v.y);
      acc[k].y += (a0 * u.y - b0 * u.x) + (a1 * v.y - b1 * v.x);
    }
  }
#pragma unroll
  for (int k = 0; k < 6; ++k) part[w][t + 64 * k] = acc[k];
  __syncthreads();
  float lamv = lamp[0];
  float oml = 1.0f - lamv;
  long pbase = b * (long)(NN * NN) + rowoff;
  for (int e = tid; e < NN; e += 256) {
    float Qx = (part[0][e].x + part[1][e].x + part[2][e].x + part[3][e].x) * (1.0f / NN);
    float Qy = (part[0][e].y + part[1][e].y + part[2][e].y + part[3][e].y) * (1.0f / NN);
    float2 yv = ybuf[pbase + e];
    float2 cz = czb[pbase + e];
    float xr = oml * (yv.x - Qx) + cz.x;
    float xi = oml * (yv.y - Qy) + cz.y;
    xr = fmaxf(xr, 0.f);
    xi = fmaxf(xi, 0.f);
    if (last) {
      outp[(b * 2 + 0) * (long)(NN * NN) + rowoff + e] = xr;
      outp[(b * 2 + 1) * (long)(NN * NN) + rowoff + e] = xi;
    } else {
      float2 xo = xbuf[pbase + e];
      xbuf[pbase + e] = make_float2(xr, xi);
      ybuf[pbase + e] = make_float2(xr + beta * (xr - xo.x), xi + beta * (xi - xo.y));
    }
  }
}

// ---------------- mask permutation precompute (one-time) -------------------
// maskPT[b][sx][y] = mask[b][y][P64(sx)], P64(s) = (s>>6) + 6*brev6(s&63).
__global__ __launch_bounds__(256) void k_mpre(const int* __restrict__ mask,
                                              unsigned char* __restrict__ maskPT) {
  long i = (long)blockIdx.x * 256 + threadIdx.x;
  long b = i / (NN * NN);
  int rem = (int)(i % (NN * NN));
  int sx = rem / NN, y = rem % NN;
  int fx = (sx >> 6) + 6 * (int)(__brev((unsigned)(sx & 63)) >> 26);
  maskPT[i] = (unsigned char)mask[b * (long)(NN * NN) + (long)y * NN + fx];
}

// ---------------- precompute: cz = (1-lam)*cst + lam*z ---------------------
__global__ __launch_bounds__(256) void k_preA(const float* __restrict__ x0,
                                              const int* __restrict__ mask,
                                              float2* __restrict__ T) {
  __shared__ float2 U[4][LNPAD], V[4][LNPAD];
  int tid = threadIdx.x;
  int line = tid >> 6, t = tid & 63;
  long gl0 = (long)blockIdx.x * 4;
#pragma unroll
  for (int k = 0; k < 6; ++k) {
    int e = tid + k * 256; int l = e / NN; int x = e % NN;
    long gl = gl0 + l;
    long b = gl / NN;
    int y = (int)(gl % NN);
    long pidx = (long)y * NN + x;
    float mv = (float)mask[b * (long)(NN * NN) + pidx];
    float br = x0[(b * 2 + 0) * (long)(NN * NN) + pidx] * mv;
    float bi = x0[(b * 2 + 1) * (long)(NN * NN) + pidx] * mv;
    U[l][LID(x)] = make_float2(br, bi);
  }
  __syncthreads();
  fft384<1>(U[line], V[line], t);
#pragma unroll
  for (int k = 0; k < 6; ++k) {
    int e = tid + k * 256; int l = e / NN; int x = e % NN;
    float2 u = U[l][LID(x)];
    T[(gl0 + l) * NN + x] = make_float2(u.x * (1.0f / NN), u.y * (1.0f / NN));
  }
}

__global__ __launch_bounds__(256) void k_preB(const float2* __restrict__ T,
                                              float2* __restrict__ r0) {
  __shared__ float2 tile[NN][17];
  __shared__ float2 U[4][LNPAD], V[4][LNPAD];
  int tid = threadIdx.x;
  int xt = blockIdx.x % (NN / 16);
  long b = blockIdx.x / (NN / 16);
  int x0c = xt * 16;
  long sbase = b * (long)(NN * NN);
#pragma unroll
  for (int k = 0; k < 24; ++k) {
    int e = tid + k * 256; int y = e >> 4; int c = e & 15;
    tile[y][c] = T[sbase + (long)y * NN + x0c + c];
  }
  __syncthreads();
  int line = tid >> 6, t = tid & 63;
  for (int g = 0; g < 4; ++g) {
#pragma unroll
    for (int k = 0; k < 6; ++k) {
      int e = tid + k * 256; int l = e / NN; int y = e % NN;
      U[l][LID(y)] = tile[y][4 * g + l];
    }
    __syncthreads();
    fft384<1>(U[line], V[line], t);
#pragma unroll
    for (int k = 0; k < 6; ++k) {
      int e = tid + k * 256; int l = e / NN; int y = e % NN;
      float2 u = U[l][LID(y)];
      tile[y][4 * g + l] = make_float2(u.x * (1.0f / NN), u.y * (1.0f / NN));
    }
    __syncthreads();
  }
#pragma unroll
  for (int k = 0; k < 24; ++k) {
    int e = tid + k * 256; int y = e >> 4; int c = e & 15;
    r0[sbase + (long)y * NN + x0c + c] = tile[y][c];
  }
}

__global__ __launch_bounds__(256) void k_preC(const float* __restrict__ csm,
                                              const float2* __restrict__ r0,
                                              const float* __restrict__ zk,
                                              const float* __restrict__ lamp,
                                              float2* __restrict__ czb) {
  long i = (long)blockIdx.x * 256 + threadIdx.x;
  long b = i / (NN * NN);
  long p = i % (NN * NN);
  float sr = 0.f, si = 0.f;
#pragma unroll
  for (int c = 0; c < CC; ++c) {
    sr += csm[(b * 2 * CC + c) * (long)(NN * NN) + p];
    si -= csm[((b * 2 + 1) * CC + c) * (long)(NN * NN) + p];
  }
  float2 r = r0[i];
  float cstx = sr * r.x - si * r.y;
  float csty = sr * r.y + si * r.x;
  float lamv = lamp[0];
  float oml = 1.0f - lamv;
  float zr = zk[(b * 2 + 0) * (long)(NN * NN) + p];
  float zi = zk[(b * 2 + 1) * (long)(NN * NN) + p];
  czb[i] = make_float2(oml * cstx + lamv * zr, oml * csty + lamv * zi);
}

extern "C" void kernel_launch(void* const* d_in, const int* in_sizes, int n_in,
                              void* d_out, int out_size, void* d_ws, size_t ws_size,
                              hipStream_t stream) {
  const float* zk  = (const float*)d_in[0];
  const float* x0  = (const float*)d_in[1];
  const float* csm = (const float*)d_in[2];
  const float* lam = (const float*)d_in[3];
  const int*   msk = (const int*)d_in[4];
  float* out = (float*)d_out;

  // ws layout (float2 units): W1 [B*C*N*N] | y | x | cz | maskPT(uchar)
  size_t img = (size_t)BB * NN * NN;
  float2* W1   = (float2*)d_ws;
  float2* ybuf = W1 + (size_t)BB * CC * NN * NN;
  float2* xbuf = ybuf + img;
  float2* czb  = xbuf + img;
  unsigned char* maskPT = (unsigned char*)(czb + img);
  float2* T  = W1;        // precompute scratch overlays W1
  float2* r0 = W1 + img;

  double tcur = 1.0;
  float betas[NITER];
  for (int i = 0; i < NITER; ++i) {
    double tn = (1.0 + sqrt(1.0 + 4.0 * tcur * tcur)) * 0.5;
    betas[i] = (float)((tcur - 1.0) / tn);
    tcur = tn;
  }

  k_mpre<<<(BB * NN * NN) / 256, 256, 0, stream>>>(msk, maskPT);
  k_preA<<<BB * NN / 4, 256, 0, stream>>>(x0, msk, T);
  k_preB<<<BB * (NN / 16), 256, 0, stream>>>(T, r0);
  k_preC<<<(BB * NN * NN) / 256, 256, 0, stream>>>(csm, r0, zk, lam, czb);
  // iteration 1 (y0 = 0): x1 = prox(cz)
  k_e<<<(BB * NN * NN) / 256, 256, 0, stream>>>(czb, xbuf, ybuf);
  // iterations 2..20: forward, mask round-trip, adjoint+update
  for (int i = 1; i < NITER; ++i) {
    k_p1<<<BB * CC * NN / 4, 256, 0, stream>>>(ybuf, csm, W1);
    k_p2<<<BB * CC * (NN / 16), 256, 0, stream>>>(W1, maskPT);
    k_p3<<<BB * NN, 256, 0, stream>>>(W1, csm, czb, lam, xbuf, ybuf, out,
                                      betas[i], (i == NITER - 1) ? 1 : 0);
  }
}